// Round 7
// baseline (884.145 us; speedup 1.0000x reference)
//
#include <hip/hip_runtime.h>
#include <cstdint>

// ---------------------------------------------------------------------------
// GatedTransformerXLLayer on MI355X (gfx950).
// D=1024, H=16, HD=64, FF=4096, CUR=256, MEM=256, BS=32, FULL=512.
// bf16 MFMA (16x16x32); 128x128 GEMM with DOUBLE-BUFFERED global_load_lds
// (stage-ahead: issue next chunk after barrier, compute, then drain) +
// XCD swizzle; fused attention with staged K/R/V, pre-scaled q, chunk
// skipping, single-pass __expf softmax with deferred 1/sum.
// ---------------------------------------------------------------------------

typedef __bf16 bf16;
typedef bf16 bf16x4 __attribute__((ext_vector_type(4)));
typedef bf16 bf16x8 __attribute__((ext_vector_type(8)));
typedef float f32x4 __attribute__((ext_vector_type(4)));

#define MFMA16(a, b, c) __builtin_amdgcn_mfma_f32_16x16x32_bf16((a), (b), (c), 0, 0, 0)

__device__ __forceinline__ void gl2lds16(const void* g, void* l) {
  __builtin_amdgcn_global_load_lds(
      (const __attribute__((address_space(1))) unsigned int*)g,
      (__attribute__((address_space(3))) unsigned int*)l, 16, 0, 0);
}

__device__ __forceinline__ bf16x8 ldg8(const bf16* p) { return *(const bf16x8*)p; }

// XOR-swizzled index into a [16][512] bf16 wave-slice (u16 units).
__device__ __forceinline__ int sidx(int row, int col) {
  return (row * 512 + col) ^ ((row & 7) << 3);
}

// ---------------- LayerNorm (one row per block, 256 thr x float4) ----------
__global__ __launch_bounds__(256) void ln_kernel(
    const float* __restrict__ src0, const float* __restrict__ src1,
    const float* __restrict__ gam, const float* __restrict__ bet,
    bf16* __restrict__ out, long ldo,
    bf16* __restrict__ raw, long ldraw, int rawstart) {
  const int row = blockIdx.x;
  const int tid = threadIdx.x;
  const float* src = (src1 != nullptr && row >= rawstart)
                         ? (src1 + (long)(row - rawstart) * 1024)
                         : (src0 + (long)row * 1024);
  float4 v = ((const float4*)src)[tid];
  float s = v.x + v.y + v.z + v.w;
#pragma unroll
  for (int o = 32; o > 0; o >>= 1) s += __shfl_down(s, o);
  __shared__ float red[8];
  const int wv = tid >> 6, lane = tid & 63;
  if (lane == 0) red[wv] = s;
  __syncthreads();
  float mean = (red[0] + red[1] + red[2] + red[3]) * (1.0f / 1024.0f);
  float dx = v.x - mean, dy = v.y - mean, dz = v.z - mean, dw = v.w - mean;
  float ss = dx * dx + dy * dy + dz * dz + dw * dw;
#pragma unroll
  for (int o = 32; o > 0; o >>= 1) ss += __shfl_down(ss, o);
  if (lane == 0) red[4 + wv] = ss;
  __syncthreads();
  float var = (red[4] + red[5] + red[6] + red[7]) * (1.0f / 1024.0f);
  float rstd = rsqrtf(var + 1e-5f);
  int c = tid * 4;
  float4 g4 = ((const float4*)gam)[tid];
  float4 b4 = ((const float4*)bet)[tid];
  bf16x4 o4;
  o4[0] = (bf16)(dx * rstd * g4.x + b4.x);
  o4[1] = (bf16)(dy * rstd * g4.y + b4.y);
  o4[2] = (bf16)(dz * rstd * g4.z + b4.z);
  o4[3] = (bf16)(dw * rstd * g4.w + b4.w);
  *(bf16x4*)(out + (long)row * ldo + c) = o4;
  if (raw != nullptr && row >= rawstart) {
    bf16x4 r4;
    r4[0] = (bf16)v.x; r4[1] = (bf16)v.y; r4[2] = (bf16)v.z; r4[3] = (bf16)v.w;
    *(bf16x4*)(raw + (long)(row - rawstart) * ldraw + c) = r4;
  }
}

// ---------------- fp32 -> bf16 convert -------------------------------------
__global__ __launch_bounds__(256) void cvt_bf16_kernel(const float* __restrict__ s,
                                                       bf16* __restrict__ d) {
  long i = ((long)blockIdx.x * 256 + threadIdx.x) * 4;
  float4 v = *(const float4*)(s + i);
  bf16x4 o;
  o[0] = (bf16)v.x; o[1] = (bf16)v.y; o[2] = (bf16)v.z; o[3] = (bf16)v.w;
  *(bf16x4*)(d + i) = o;
}

// ---------------- batched weight transpose+convert -------------------------
struct TDesc { const float* src; bf16* dst; int N; int ldd; int start; };
struct TPack { TDesc d[18]; int nd; int total; };

__global__ __launch_bounds__(256) void wtrans_multi(TPack p) {
  __shared__ bf16 t[64][66];
  const int tile = blockIdx.x;
  int wi = 0;
#pragma unroll 1
  for (int i = 1; i < p.nd; ++i)
    if (tile >= p.d[i].start) wi = i;
  const float* src = p.d[wi].src;
  bf16* dst = p.d[wi].dst;
  const int N = p.d[wi].N;
  const long ldd = p.d[wi].ldd;
  const int local = tile - p.d[wi].start;
  const int tiles_x = N >> 6;
  const int n0 = (local % tiles_x) * 64, k0 = (local / tiles_x) * 64;
  const int tx = threadIdx.x & 63, ty = threadIdx.x >> 6;
#pragma unroll
  for (int i = 0; i < 64; i += 4)
    t[ty + i][tx] = (bf16)src[(long)(k0 + ty + i) * N + n0 + tx];
  __syncthreads();
#pragma unroll
  for (int i = 0; i < 64; i += 4)
    dst[(long)(n0 + ty + i) * ldd + k0 + tx] = t[tx][ty + i];
}

// ---------------- V transpose: Vbuf[t][1024] -> valT[(b*16+h)*64+d][j] -----
__global__ __launch_bounds__(256) void valt_kernel(const bf16* __restrict__ Vbuf,
                                                   bf16* __restrict__ valT) {
  __shared__ bf16 t[64][66];
  const int b = blockIdx.x, h = blockIdx.y, j0 = blockIdx.z * 64;
  const int jj = threadIdx.x >> 2, dg = (threadIdx.x & 3) * 16;
  const bf16* srcp = Vbuf + ((long)(j0 + jj) * 32 + b) * 1024 + h * 64 + dg;
  bf16x8 v0 = ldg8(srcp), v1 = ldg8(srcp + 8);
#pragma unroll
  for (int e = 0; e < 8; ++e) { t[jj][dg + e] = v0[e]; t[jj][dg + 8 + e] = v1[e]; }
  __syncthreads();
  const int dd = threadIdx.x >> 2, jg = (threadIdx.x & 3) * 16;
  bf16* dstp = valT + ((long)(b * 16 + h) * 64 + dd) * 512 + j0 + jg;
  bf16x8 o0, o1;
#pragma unroll
  for (int e = 0; e < 8; ++e) { o0[e] = t[jg + e][dd]; o1[e] = t[jg + 8 + e][dd]; }
  *(bf16x8*)dstp = o0;
  *(bf16x8*)(dstp + 8) = o1;
}

// ---------------- fused attention -----------------------------------------
__device__ __forceinline__ void stageKR(const char* rowbase, long strideB,
                                        bf16* stg, int tid) {
#pragma unroll
  for (int i = 0; i < 4; ++i) {
    const int slot = i * 256 + tid;
    const int row = slot >> 3;
    const int colb = ((slot << 4) & 127) ^ ((row & 7) << 4);
    gl2lds16(rowbase + (long)row * strideB + colb, (char*)stg + slot * 16);
  }
}
__device__ __forceinline__ void stageV(const char* rowbase, long strideB,
                                       bf16* stg, int tid) {
#pragma unroll
  for (int i = 0; i < 4; ++i) {
    const int slot = i * 256 + tid;
    const int row = slot >> 4;
    const int colb = ((slot << 4) & 255) ^ ((row & 7) << 4);
    gl2lds16(rowbase + (long)row * strideB + colb, (char*)stg + slot * 16);
  }
}
__device__ __forceinline__ bf16x8 rdKR(const bf16* stg, int rloc, int byteInRow) {
  const int addr = (rloc * 128 + byteInRow) ^ ((rloc & 7) << 4);
  return *(const bf16x8*)((const char*)stg + addr);
}
__device__ __forceinline__ bf16x8 rdV(const bf16* stg, int rloc, int byteInRow) {
  const int addr = (rloc * 256 + byteInRow) ^ ((rloc & 7) << 4);
  return *(const bf16x8*)((const char*)stg + addr);
}

__global__ __launch_bounds__(256, 2) void attn_kernel(
    const bf16* __restrict__ qb, const float* __restrict__ uvec,
    const float* __restrict__ vvec, const bf16* __restrict__ Kb,
    const bf16* __restrict__ rbf, const bf16* __restrict__ valT,
    bf16* __restrict__ a1out) {
  __shared__ __align__(16) bf16 s2[4][8192];   // 64KB wave-private S2/logit/P
  __shared__ __align__(16) bf16 stg[8192];     // 16KB shared staging
  const int tid = threadIdx.x;
  const int wv = tid >> 6, lane = tid & 63;
  const int l15 = lane & 15, lk = lane >> 4;
  const int bid = blockIdx.x;
  const int swzb = ((bid & 7) << 8) + (bid >> 3);  // nwg=2048, 256-chunks/XCD
  const int st = swzb & 3, h = (swzb >> 2) & 15, b = swzb >> 6;
  const int i0 = st * 64 + wv * 16;
  const long bh = (long)b * 16 + h;
  bf16* sw = s2[wv];
  const bool skipE = (st < 2);  // block-uniform masked-chunk skip

  const bf16* qp = qb + ((long)(i0 + l15) * 32 + b) * 1024 + h * 64 + lk * 8;
  bf16x8 q0 = ldg8(qp), q1 = ldg8(qp + 32);
  const float* up = uvec + h * 64 + lk * 8;
  const float* vp = vvec + h * 64 + lk * 8;
  bf16x8 a0u, a1u, a0v, a1v;
#pragma unroll
  for (int e = 0; e < 8; ++e) {
    float f0 = (float)q0[e], f1 = (float)q1[e];
    a0u[e] = (bf16)((f0 + up[e]) * 0.125f);
    a1u[e] = (bf16)((f1 + up[32 + e]) * 0.125f);
    a0v[e] = (bf16)((f0 + vp[e]) * 0.125f);
    a1v[e] = (bf16)((f1 + vp[32 + e]) * 0.125f);
  }

  // ---- Phase 1: S2 = (q+v)/8 R^T -> wave-private LDS, cols = raw index
#pragma unroll
  for (int c = 0; c < 4; ++c) {
    if (skipE && c == 0) continue;
    __syncthreads();
    stageKR((const char*)(rbf + (long)(c * 128) * 1024 + h * 64), 2048, stg, tid);
    __syncthreads();
#pragma unroll
    for (int jt = 0; jt < 8; ++jt) {
      bf16x8 b0 = rdKR(stg, jt * 16 + l15, lk * 16);
      bf16x8 b1 = rdKR(stg, jt * 16 + l15, 64 + lk * 16);
      f32x4 cc = {0.f, 0.f, 0.f, 0.f};
      cc = MFMA16(a0v, b0, cc);
      cc = MFMA16(a1v, b1, cc);
      const int jcol = (c * 8 + jt) * 16 + l15;
#pragma unroll
      for (int r = 0; r < 4; ++r) sw[sidx(lk * 4 + r, jcol)] = (bf16)cc[r];
    }
  }
  // ---- Phase 2: logits in-place (gather cols >= write col; wave-private)
#pragma unroll
  for (int c = 0; c < 4; ++c) {
    if (skipE && c == 3) continue;
    __syncthreads();
    stageKR((const char*)(Kb + ((long)(c * 128) * 32 + b) * 1024 + h * 64),
            65536, stg, tid);
    __syncthreads();
#pragma unroll
    for (int jt = 0; jt < 8; ++jt) {
      bf16x8 b0 = rdKR(stg, jt * 16 + l15, lk * 16);
      bf16x8 b1 = rdKR(stg, jt * 16 + l15, 64 + lk * 16);
      f32x4 cc = {0.f, 0.f, 0.f, 0.f};
      cc = MFMA16(a0u, b0, cc);
      cc = MFMA16(a1u, b1, cc);
      const int j = (c * 8 + jt) * 16 + l15;
      float lgv[4];
#pragma unroll
      for (int r = 0; r < 4; ++r) {
        const int i = i0 + lk * 4 + r;
        lgv[r] = (j <= i + 256)
                     ? (cc[r] + (float)sw[sidx(lk * 4 + r, j - i + 255)])
                     : -1e30f;
      }
#pragma unroll
      for (int r = 0; r < 4; ++r) sw[sidx(lk * 4 + r, j)] = (bf16)lgv[r];
    }
  }
  // ---- single-pass softmax, unnormalized; 1/sum deferred to PV epilogue
  float inv;
  {
    const int rr = lane & 15, pp = lane >> 4;
    const bool dead = skipE && (pp == 3);
    bf16x8 pk[16];
    float m = -3e38f;
    if (!dead) {
#pragma unroll
      for (int k = 0; k < 16; ++k)
        pk[k] = *(const bf16x8*)(sw + sidx(rr, pp * 128 + k * 8));
#pragma unroll
      for (int k = 0; k < 16; ++k)
#pragma unroll
        for (int e = 0; e < 8; ++e) m = fmaxf(m, (float)pk[k][e]);
    }
    m = fmaxf(m, __shfl_xor(m, 16));
    m = fmaxf(m, __shfl_xor(m, 32));
    float s = 0.f;
    if (!dead) {
#pragma unroll
      for (int k = 0; k < 16; ++k) {
        bf16x8 t;
#pragma unroll
        for (int e = 0; e < 8; ++e) {
          float ev = __expf((float)pk[k][e] - m);
          s += ev;
          t[e] = (bf16)ev;
        }
        *(bf16x8*)(sw + sidx(rr, pp * 128 + k * 8)) = t;
      }
    }
    s += __shfl_xor(s, 16);
    s += __shfl_xor(s, 32);
    inv = 1.0f / s;
  }
  // ---- Phase 3: O = (P V) * inv
  f32x4 oacc[4] = {};
  const char* vbase = (const char*)(valT + bh * 64 * 512);
#pragma unroll
  for (int c = 0; c < 4; ++c) {
    if (skipE && c == 3) continue;
    __syncthreads();
    stageV(vbase + c * 256, 1024, stg, tid);
    __syncthreads();
#pragma unroll
    for (int ksl = 0; ksl < 4; ++ksl) {
      const int ks = c * 4 + ksl;
      bf16x8 pa = *(const bf16x8*)(sw + sidx(l15, ks * 32 + lk * 8));
#pragma unroll
      for (int nt = 0; nt < 4; ++nt) {
        bf16x8 vb = rdV(stg, nt * 16 + l15, ksl * 64 + lk * 16);
        oacc[nt] = MFMA16(pa, vb, oacc[nt]);
      }
    }
  }
  float invr[4];
#pragma unroll
  for (int r = 0; r < 4; ++r) invr[r] = __shfl(inv, lk * 4 + r);
#pragma unroll
  for (int nt = 0; nt < 4; ++nt)
#pragma unroll
    for (int r = 0; r < 4; ++r) {
      const long t = (long)(i0 + lk * 4 + r) * 32 + b;
      a1out[t * 1024 + h * 64 + nt * 16 + l15] = (bf16)(oacc[nt][r] * invr[r]);
    }
}

// ---------------- generic 128x128 MFMA GEMM with fused epilogues -----------
// Double-buffered stage-ahead K-loop (T3 "minimum 2-phase"): after each
// barrier, ISSUE next chunk's global_load_lds, then compute current chunk;
// the compiler's vmcnt(0)-drain before the next s_barrier lands after the
// MFMAs, hiding HBM/L2 latency. One barrier per 32-K step. K % 64 == 0.
enum { EP_B16 = 0, EP_KV2 = 1, EP_GELU = 2, EP_SIGRX = 3, EP_GRU = 4 };

struct GP {
  const bf16* A0; const bf16* A1;   // A split at k=ksplit (concat-K GEMMs)
  long lda0, lda1; int ksplit; int K;
  const bf16* B;                    // [N][K] bf16 (W^T), row stride K
  const float* bias;
  const float* bg;                  // EP_SIGRX
  const float* xbuf;                // EP_SIGRX (r*x), EP_GRU (combine x), f32
  const bf16* zbuf;                 // EP_GRU (z, bf16)
  float* outf; long ldf;
  bf16* outb; long ldb;
  bf16* outb2; long ldb2;
};

template <int EP>
__global__ __launch_bounds__(256, 3) void gemm_bt(GP p) {
  __shared__ __align__(16) bf16 As[2][128 * 32];
  __shared__ __align__(16) bf16 Bs[2][128 * 32];
  const int tid = threadIdx.x;
  const int lane = tid & 63;
  const int wv = tid >> 6;
  const int wr = wv >> 1, wc = wv & 1;
  const int l15 = lane & 15, lk = lane >> 4;
  const int nx = gridDim.x;
  const int nwg = nx * gridDim.y;
  const int bid = blockIdx.y * nx + blockIdx.x;
  const int qq = nwg >> 3, rr = nwg & 7, xc = bid & 7, loc = bid >> 3;
  const int swz = (xc < rr ? xc * (qq + 1) : rr * (qq + 1) + (xc - rr) * qq) + loc;
  const long n0 = (long)(swz % nx) * 128;
  const long m0 = (long)(swz / nx) * 128;
  const int srow = tid >> 2;
  const int skk = (tid & 3) * 8;
  const long sdst = (long)srow * 32 + skk;

  const bf16* Bg0 = p.B + (n0 + srow) * (long)p.K + skk;
  const bf16* Bg1 = p.B + (n0 + srow + 64) * (long)p.K + skk;

  auto stage = [&](int k0, int bb) {
    const bf16 *ag0, *ag1;
    if (k0 < p.ksplit) {
      ag0 = p.A0 + (m0 + srow) * p.lda0 + k0 + skk;
      ag1 = p.A0 + (m0 + srow + 64) * p.lda0 + k0 + skk;
    } else {
      ag0 = p.A1 + (m0 + srow) * p.lda1 + (k0 - p.ksplit) + skk;
      ag1 = p.A1 + (m0 + srow + 64) * p.lda1 + (k0 - p.ksplit) + skk;
    }
    gl2lds16(ag0, As[bb] + sdst);
    gl2lds16(ag1, As[bb] + 64 * 32 + sdst);
    gl2lds16(Bg0 + k0, Bs[bb] + sdst);
    gl2lds16(Bg1 + k0, Bs[bb] + 64 * 32 + sdst);
  };

  f32x4 acc[4][4] = {};

  auto compute = [&](int bb) {
    bf16x8 af[4], bfr[4];
#pragma unroll
    for (int i = 0; i < 4; ++i) {
      af[i] = *(const bf16x8*)(As[bb] + (wr * 64 + i * 16 + l15) * 32 + lk * 8);
      bfr[i] = *(const bf16x8*)(Bs[bb] + (wc * 64 + i * 16 + l15) * 32 + lk * 8);
    }
#pragma unroll
    for (int i = 0; i < 4; ++i)
#pragma unroll
      for (int j = 0; j < 4; ++j) acc[i][j] = MFMA16(af[i], bfr[j], acc[i][j]);
  };

  stage(0, 0);
#pragma unroll 1
  for (int k0 = 0; k0 < p.K; k0 += 64) {
    __syncthreads();               // buf0 staged (vmcnt drained); buf1 reads done
    stage(k0 + 32, 1);             // issue-ahead (K%64==0 -> always valid)
    compute(0);                    // overlaps buf1 staging
    __syncthreads();               // buf1 staged; buf0 reads done
    if (k0 + 64 < p.K) stage(k0 + 64, 0);
    compute(1);
  }

#pragma unroll
  for (int i = 0; i < 4; ++i) {
#pragma unroll
    for (int j = 0; j < 4; ++j) {
#pragma unroll
      for (int r = 0; r < 4; ++r) {
        const long row = m0 + wr * 64 + i * 16 + lk * 4 + r;
        const long col = n0 + wc * 64 + j * 16 + l15;
        float v = acc[i][j][r];
        if constexpr (EP == EP_B16) {
          v += p.bias[col];
          p.outb[row * p.ldb + col] = (bf16)v;
        } else if constexpr (EP == EP_KV2) {
          v += p.bias[col];
          if (col < 1024) p.outb[row * p.ldb + col] = (bf16)v;          // K
          else p.outb2[row * p.ldb2 + (col - 1024)] = (bf16)v;          // V
        } else if constexpr (EP == EP_GELU) {
          v += p.bias[col];
          float g = 0.5f * v * (1.0f + erff(v * 0.70710678118654752f));
          p.outb[row * p.ldb + col] = (bf16)g;
        } else if constexpr (EP == EP_SIGRX) {
          if (col >= 1024) {
            float sg = 1.0f / (1.0f + __expf(-(v - p.bg[col - 1024])));
            p.outb2[row * p.ldb2 + (col - 1024)] = (bf16)sg;            // z
          } else {
            float sg = 1.0f / (1.0f + __expf(-v));
            p.outb[row * p.ldb + col] = (bf16)(sg * p.xbuf[row * 1024 + col]);  // r*x
          }
        } else if constexpr (EP == EP_GRU) {
          float z = (float)p.zbuf[row * 1024 + col];
          float x = p.xbuf[row * 1024 + col];
          float vc = fminf(fmaxf(v, -15.f), 15.f);
          float e2 = __expf(2.0f * vc);
          float th = (e2 - 1.0f) / (e2 + 1.0f);
          float o = (1.0f - z) * x + z * th;
          p.outf[row * p.ldf + col] = o;
          if (p.outb != nullptr) p.outb[row * p.ldb + col] = (bf16)o;
        }
      }
    }
  }
}

// ---------------------------------------------------------------------------
extern "C" void kernel_launch(void* const* d_in, const int* in_sizes, int n_in,
                              void* d_out, int out_size, void* d_ws, size_t ws_size,
                              hipStream_t stream) {
  const float* inputs = (const float*)d_in[0];
  const float* posemb = (const float*)d_in[1];
  const float* u_in = (const float*)d_in[2];
  const float* v_in = (const float*)d_in[3];
  const float* memory = (const float*)d_in[4];
  // d_in[5] = mask: analytic (unmasked iff j <= i+256), not read.
  const float* ln1_g = (const float*)d_in[6];
  const float* ln1_b = (const float*)d_in[7];
  const float* ln2_g = (const float*)d_in[8];
  const float* ln2_b = (const float*)d_in[9];
  const float* W_kv = (const float*)d_in[10];
  const float* b_kv = (const float*)d_in[11];
  const float* W_q = (const float*)d_in[12];
  const float* b_q = (const float*)d_in[13];
  const float* W_pos = (const float*)d_in[14];
  const float* b_pos = (const float*)d_in[15];
  const float* W_o = (const float*)d_in[16];
  const float* b_o = (const float*)d_in[17];
  const float* g1_Wr = (const float*)d_in[18];
  const float* g1_Ur = (const float*)d_in[19];
  const float* g1_Wz = (const float*)d_in[20];
  const float* g1_Uz = (const float*)d_in[21];
  const float* g1_Wg = (const float*)d_in[22];
  const float* g1_Ug = (const float*)d_in[23];
  const float* g1_bg = (const float*)d_in[24];
  const float* g2_Wr = (const float*)d_in[25];
  const float* g2_Ur = (const float*)d_in[26];
  const float* g2_Wz = (const float*)d_in[27];
  const float* g2_Uz = (const float*)d_in[28];
  const float* g2_Wg = (const float*)d_in[29];
  const float* g2_Ug = (const float*)d_in[30];
  const float* g2_bg = (const float*)d_in[31];
  const float* W_m1 = (const float*)d_in[32];
  const float* b_m1 = (const float*)d_in[33];
  const float* W_m2 = (const float*)d_in[34];
  const float* b_m2 = (const float*)d_in[35];
  float* out = (float*)d_out;
  float* o1 = out;  // f32 o1 parked in d_out (fully rewritten s11, read 12/15/16)

  const size_t MB = 1024UL * 1024UL;
  const size_t sizeB = 154 * MB;
  const size_t sizeA = 196 * MB;
  const bool A = (ws_size >= sizeA);
  if (!A && ws_size < sizeB) {  // canary: absmax ~3.4e38 => ws too small
    hipMemsetAsync(d_out, 0x7F, 256, stream);
    return;
  }

  char* w = (char*)d_ws;
  size_t off = 0;
  auto take = [&](size_t bytes) { char* p = w + off; off += bytes; return p; };
  char* RW = take(A ? 50 * MB : 8 * MB);
  bf16* posbf = (bf16*)take(1 * MB);
  bf16* rbf = (bf16*)take(1 * MB);
  char* R3 = take(32 * MB);   // x1(1-4) | valT(7-8) | y1@0(9-11), x2@16M(12-13) | m2@0(14-16)
  char* R45 = take(64 * MB);  // Kbuf@0 + Vbuf@32M (4-8) | mh 64MB (13-14)
  char* R6 = take(16 * MB);   // xb16(1-10) | o1b(11-16)
  char* R7 = take(16 * MB);   // qb(5-8) | rx(10-16)
  char* R8 = take(16 * MB);   // a1b(8-9) | z1b(10-16)

  bf16* WT = (bf16*)RW;
  bf16* WkvT  = A ? (bf16*)(RW + 0 * MB)  : WT;
  bf16* WqT   = A ? (bf16*)(RW + 4 * MB)  : WT;
  bf16* WposT = A ? (bf16*)(RW + 6 * MB)  : WT;
  bf16* WoT   = A ? (bf16*)(RW + 8 * MB)  : WT;
  bf16* G1rz  = A ? (bf16*)(RW + 10 * MB) : WT;
  bf16* G1g   = A ? (bf16*)(RW + 18 * MB) : WT;
  bf16* Wm1T  = A ? (bf16*)(RW + 22 * MB) : WT;
  bf16* Wm2T  = A ? (bf16*)(RW + 30 * MB) : WT;
  bf16* G2rz  = A ? (bf16*)(RW + 38 * MB) : WT;
  bf16* G2g   = A ? (bf16*)(RW + 46 * MB) : WT;

  bf16* x1 = (bf16*)R3;
  bf16* valT = (bf16*)R3;
  bf16* y1 = (bf16*)R3;
  bf16* x2 = (bf16*)(R3 + 16 * MB);
  bf16* m2 = (bf16*)R3;
  bf16* Kbuf = (bf16*)R45;
  bf16* Vbuf = (bf16*)(R45 + 32 * MB);
  bf16* mh = (bf16*)R45;
  bf16* xb16 = (bf16*)R6;
  bf16* o1b = (bf16*)R6;
  bf16* qb = (bf16*)R7;
  bf16* rx = (bf16*)R7;
  bf16* a1b = (bf16*)R8;
  bf16* z1b = (bf16*)R8;

  dim3 blk(256);
  auto addT = [](TPack& p, const float* src, bf16* dst, int K, int N, int ldd) {
    TDesc& d = p.d[p.nd++];
    d.src = src; d.dst = dst; d.N = N; d.ldd = ldd; d.start = p.total;
    p.total += (N / 64) * (K / 64);
  };
  auto runT = [&](TPack& p) {
    wtrans_multi<<<dim3(p.total), blk, 0, stream>>>(p);
  };
  auto T_kv = [&](TPack& p) { addT(p, W_kv, WkvT, 1024, 2048, 1024); };
  auto T_q = [&](TPack& p) { addT(p, W_q, WqT, 1024, 1024, 1024); };
  auto T_pos = [&](TPack& p) { addT(p, W_pos, WposT, 1024, 1024, 1024); };
  auto T_o = [&](TPack& p) { addT(p, W_o, WoT, 1024, 1024, 1024); };
  auto T_g1rz = [&](TPack& p) {
    addT(p, g1_Wr, G1rz, 1024, 1024, 2048);
    addT(p, g1_Ur, G1rz + 1024, 1024, 1024, 2048);
    addT(p, g1_Wz, G1rz + 1024L * 2048, 1024, 1024, 2048);
    addT(p, g1_Uz, G1rz + 1024L * 2048 + 1024, 1024, 1024, 2048);
  };
  auto T_g1g = [&](TPack& p) {
    addT(p, g1_Wg, G1g, 1024, 1024, 2048);
    addT(p, g1_Ug, G1g + 1024, 1024, 1024, 2048);
  };
  auto T_m1 = [&](TPack& p) { addT(p, W_m1, Wm1T, 1024, 4096, 1024); };
  auto T_m2 = [&](TPack& p) { addT(p, W_m2, Wm2T, 4096, 1024, 4096); };
  auto T_g2rz = [&](TPack& p) {
    addT(p, g2_Wr, G2rz, 1024, 1024, 2048);
    addT(p, g2_Ur, G2rz + 1024, 1024, 1024, 2048);
    addT(p, g2_Wz, G2rz + 1024L * 2048, 1024, 1024, 2048);
    addT(p, g2_Uz, G2rz + 1024L * 2048 + 1024, 1024, 1024, 2048);
  };
  auto T_g2g = [&](TPack& p) {
    addT(p, g2_Wg, G2g, 1024, 1024, 2048);
    addT(p, g2_Ug, G2g + 1024, 1024, 1024, 2048);
  };
  auto maybeT = [&](auto builder) {
    if (!A) { TPack p{}; builder(p); runT(p); }
  };

  if (A) {  // one batched transpose for all 18 weights
    TPack p{};
    T_kv(p); T_q(p); T_pos(p); T_o(p); T_g1rz(p); T_g1g(p);
    T_m1(p); T_m2(p); T_g2rz(p); T_g2g(p);
    runT(p);
  }

  // 1. LN1 over [memory; inputs] -> x1; raw inputs bf16 -> xb16
  ln_kernel<<<16384, blk, 0, stream>>>(memory, inputs, ln1_g, ln1_b, x1, 1024,
                                       xb16, 1024, 8192);
  // 2. pos_embedding -> bf16
  cvt_bf16_kernel<<<512, blk, 0, stream>>>(posemb, posbf);

  // 4. kv GEMM: K -> Kbuf, V -> Vbuf (both coalesced)
  maybeT(T_kv);
  {
    GP p{};
    p.A0 = p.A1 = x1; p.lda0 = p.lda1 = 1024; p.ksplit = 1 << 30; p.K = 1024;
    p.B = WkvT; p.bias = b_kv; p.outb = Kbuf; p.ldb = 1024;
    p.outb2 = Vbuf; p.ldb2 = 1024;
    gemm_bt<EP_KV2><<<dim3(16, 128), blk, 0, stream>>>(p);
  }
  // 5. q = inputs @ W_q + b_q -> qb (u/v added inside attention)
  maybeT(T_q);
  {
    GP p{};
    p.A0 = p.A1 = xb16; p.lda0 = p.lda1 = 1024; p.ksplit = 1 << 30; p.K = 1024;
    p.B = WqT; p.bias = b_q; p.outb = qb; p.ldb = 1024;
    gemm_bt<EP_B16><<<dim3(8, 64), blk, 0, stream>>>(p);
  }
  // 6. r = pos_embedding @ W_pos + b_pos -> rbf
  maybeT(T_pos);
  {
    GP p{};
    p.A0 = p.A1 = posbf; p.lda0 = p.lda1 = 1024; p.ksplit = 1 << 30; p.K = 1024;
    p.B = WposT; p.bias = b_pos; p.outb = rbf; p.ldb = 1024;
    gemm_bt<EP_B16><<<dim3(8, 4), blk, 0, stream>>>(p);
  }
  // 7. V transpose (x1 dead; valT overlays R3)
  valt_kernel<<<dim3(32, 16, 8), blk, 0, stream>>>(Vbuf, valT);
  // 8. fused attention -> a1b
  attn_kernel<<<dim3(2048), blk, 0, stream>>>(qb, u_in, v_in, Kbuf, rbf, valT, a1b);
  // 9. y1 = gelu(a1 @ W_o + b_o)
  maybeT(T_o);
  {
    GP p{};
    p.A0 = p.A1 = a1b; p.lda0 = p.lda1 = 1024; p.ksplit = 1 << 30; p.K = 1024;
    p.B = WoT; p.bias = b_o; p.outb = y1; p.ldb = 1024;
    gemm_bt<EP_GELU><<<dim3(8, 64), blk, 0, stream>>>(p);
  }
  // 10. gate1 r/z: [y1|x] @ [Wr Ur; Wz Uz]; r*x -> rx, z -> z1b
  maybeT(T_g1rz);
  {
    GP p{};
    p.A0 = y1; p.lda0 = 1024; p.A1 = xb16; p.lda1 = 1024; p.ksplit = 1024; p.K = 2048;
    p.B = G1rz; p.bg = g1_bg; p.xbuf = inputs;
    p.outb = rx; p.ldb = 1024; p.outb2 = z1b; p.ldb2 = 1024;
    gemm_bt<EP_SIGRX><<<dim3(16, 64), blk, 0, stream>>>(p);
  }
  // 11. gate1 h + combine: o1 = (1-z)*x + z*tanh([y1|rx] @ [Wg;Ug])
  maybeT(T_g1g);
  {
    GP p{};
    p.A0 = y1; p.lda0 = 1024; p.A1 = rx; p.lda1 = 1024; p.ksplit = 1024; p.K = 2048;
    p.B = G1g; p.zbuf = z1b; p.xbuf = inputs;
    p.outf = o1; p.ldf = 1024; p.outb = o1b; p.ldb = 1024;
    gemm_bt<EP_GRU><<<dim3(8, 64), blk, 0, stream>>>(p);
  }
  // 12. LN2(o1) -> x2
  ln_kernel<<<8192, blk, 0, stream>>>(o1, nullptr, ln2_g, ln2_b, x2, 1024,
                                      nullptr, 0, 1 << 30);
  // 13. mh = gelu(x2 @ W_m1 + b_m1)
  maybeT(T_m1);
  {
    GP p{};
    p.A0 = p.A1 = x2; p.lda0 = p.lda1 = 1024; p.ksplit = 1 << 30; p.K = 1024;
    p.B = Wm1T; p.bias = b_m1; p.outb = mh; p.ldb = 4096;
    gemm_bt<EP_GELU><<<dim3(32, 64), blk, 0, stream>>>(p);
  }
  // 14. m2 = gelu(mh @ W_m2 + b_m2)
  maybeT(T_m2);
  {
    GP p{};
    p.A0 = p.A1 = mh; p.lda0 = p.lda1 = 4096; p.ksplit = 1 << 30; p.K = 4096;
    p.B = Wm2T; p.bias = b_m2; p.outb = m2; p.ldb = 1024;
    gemm_bt<EP_GELU><<<dim3(8, 64), blk, 0, stream>>>(p);
  }
  // 15. gate2 r/z: [m2|o1b]; r*o1 -> rx, z -> z1b
  maybeT(T_g2rz);
  {
    GP p{};
    p.A0 = m2; p.lda0 = 1024; p.A1 = o1b; p.lda1 = 1024; p.ksplit = 1024; p.K = 2048;
    p.B = G2rz; p.bg = g2_bg; p.xbuf = o1;
    p.outb = rx; p.ldb = 1024; p.outb2 = z1b; p.ldb2 = 1024;
    gemm_bt<EP_SIGRX><<<dim3(16, 64), blk, 0, stream>>>(p);
  }
  // 16. gate2 h + combine -> d_out (in-place over o1: own-element read/write)
  maybeT(T_g2g);
  {
    GP p{};
    p.A0 = m2; p.lda0 = 1024; p.A1 = rx; p.lda1 = 1024; p.ksplit = 1024; p.K = 2048;
    p.B = G2g; p.zbuf = z1b; p.xbuf = o1;
    p.outf = out; p.ldf = 1024; p.outb = nullptr;
    gemm_bt<EP_GRU><<<dim3(8, 64), blk, 0, stream>>>(p);
  }
}

// Round 8
// 854.473 us; speedup vs baseline: 1.0347x; 1.0347x over previous
//
#include <hip/hip_runtime.h>
#include <cstdint>

// ---------------------------------------------------------------------------
// GatedTransformerXLLayer on MI355X (gfx950).
// D=1024, H=16, HD=64, FF=4096, CUR=256, MEM=256, BS=32, FULL=512.
// bf16 MFMA (16x16x32); 128x128 GEMM with 3-SLOT RING LDS + counted
// s_waitcnt vmcnt(4) + raw s_barrier (never drain-to-0 in loop; T4
// mechanism, m218) + XCD swizzle + setprio around MFMA cluster (T5);
// fused attention with staged K/R/V, pre-scaled q, chunk skipping,
// single-pass __expf softmax with deferred 1/sum.
// ---------------------------------------------------------------------------

typedef __bf16 bf16;
typedef bf16 bf16x4 __attribute__((ext_vector_type(4)));
typedef bf16 bf16x8 __attribute__((ext_vector_type(8)));
typedef float f32x4 __attribute__((ext_vector_type(4)));

#define MFMA16(a, b, c) __builtin_amdgcn_mfma_f32_16x16x32_bf16((a), (b), (c), 0, 0, 0)

__device__ __forceinline__ void gl2lds16(const void* g, void* l) {
  __builtin_amdgcn_global_load_lds(
      (const __attribute__((address_space(1))) unsigned int*)g,
      (__attribute__((address_space(3))) unsigned int*)l, 16, 0, 0);
}

__device__ __forceinline__ bf16x8 ldg8(const bf16* p) { return *(const bf16x8*)p; }

// XOR-swizzled index into a [16][512] bf16 wave-slice (u16 units).
__device__ __forceinline__ int sidx(int row, int col) {
  return (row * 512 + col) ^ ((row & 7) << 3);
}

// ---------------- LayerNorm (one row per block, 256 thr x float4) ----------
__global__ __launch_bounds__(256) void ln_kernel(
    const float* __restrict__ src0, const float* __restrict__ src1,
    const float* __restrict__ gam, const float* __restrict__ bet,
    bf16* __restrict__ out, long ldo,
    bf16* __restrict__ raw, long ldraw, int rawstart) {
  const int row = blockIdx.x;
  const int tid = threadIdx.x;
  const float* src = (src1 != nullptr && row >= rawstart)
                         ? (src1 + (long)(row - rawstart) * 1024)
                         : (src0 + (long)row * 1024);
  float4 v = ((const float4*)src)[tid];
  float s = v.x + v.y + v.z + v.w;
#pragma unroll
  for (int o = 32; o > 0; o >>= 1) s += __shfl_down(s, o);
  __shared__ float red[8];
  const int wv = tid >> 6, lane = tid & 63;
  if (lane == 0) red[wv] = s;
  __syncthreads();
  float mean = (red[0] + red[1] + red[2] + red[3]) * (1.0f / 1024.0f);
  float dx = v.x - mean, dy = v.y - mean, dz = v.z - mean, dw = v.w - mean;
  float ss = dx * dx + dy * dy + dz * dz + dw * dw;
#pragma unroll
  for (int o = 32; o > 0; o >>= 1) ss += __shfl_down(ss, o);
  if (lane == 0) red[4 + wv] = ss;
  __syncthreads();
  float var = (red[4] + red[5] + red[6] + red[7]) * (1.0f / 1024.0f);
  float rstd = rsqrtf(var + 1e-5f);
  int c = tid * 4;
  float4 g4 = ((const float4*)gam)[tid];
  float4 b4 = ((const float4*)bet)[tid];
  bf16x4 o4;
  o4[0] = (bf16)(dx * rstd * g4.x + b4.x);
  o4[1] = (bf16)(dy * rstd * g4.y + b4.y);
  o4[2] = (bf16)(dz * rstd * g4.z + b4.z);
  o4[3] = (bf16)(dw * rstd * g4.w + b4.w);
  *(bf16x4*)(out + (long)row * ldo + c) = o4;
  if (raw != nullptr && row >= rawstart) {
    bf16x4 r4;
    r4[0] = (bf16)v.x; r4[1] = (bf16)v.y; r4[2] = (bf16)v.z; r4[3] = (bf16)v.w;
    *(bf16x4*)(raw + (long)(row - rawstart) * ldraw + c) = r4;
  }
}

// ---------------- fp32 -> bf16 convert -------------------------------------
__global__ __launch_bounds__(256) void cvt_bf16_kernel(const float* __restrict__ s,
                                                       bf16* __restrict__ d) {
  long i = ((long)blockIdx.x * 256 + threadIdx.x) * 4;
  float4 v = *(const float4*)(s + i);
  bf16x4 o;
  o[0] = (bf16)v.x; o[1] = (bf16)v.y; o[2] = (bf16)v.z; o[3] = (bf16)v.w;
  *(bf16x4*)(d + i) = o;
}

// ---------------- batched weight transpose+convert -------------------------
struct TDesc { const float* src; bf16* dst; int N; int ldd; int start; };
struct TPack { TDesc d[18]; int nd; int total; };

__global__ __launch_bounds__(256) void wtrans_multi(TPack p) {
  __shared__ bf16 t[64][66];
  const int tile = blockIdx.x;
  int wi = 0;
#pragma unroll 1
  for (int i = 1; i < p.nd; ++i)
    if (tile >= p.d[i].start) wi = i;
  const float* src = p.d[wi].src;
  bf16* dst = p.d[wi].dst;
  const int N = p.d[wi].N;
  const long ldd = p.d[wi].ldd;
  const int local = tile - p.d[wi].start;
  const int tiles_x = N >> 6;
  const int n0 = (local % tiles_x) * 64, k0 = (local / tiles_x) * 64;
  const int tx = threadIdx.x & 63, ty = threadIdx.x >> 6;
#pragma unroll
  for (int i = 0; i < 64; i += 4)
    t[ty + i][tx] = (bf16)src[(long)(k0 + ty + i) * N + n0 + tx];
  __syncthreads();
#pragma unroll
  for (int i = 0; i < 64; i += 4)
    dst[(long)(n0 + ty + i) * ldd + k0 + tx] = t[tx][ty + i];
}

// ---------------- V transpose: Vbuf[t][1024] -> valT[(b*16+h)*64+d][j] -----
__global__ __launch_bounds__(256) void valt_kernel(const bf16* __restrict__ Vbuf,
                                                   bf16* __restrict__ valT) {
  __shared__ bf16 t[64][66];
  const int b = blockIdx.x, h = blockIdx.y, j0 = blockIdx.z * 64;
  const int jj = threadIdx.x >> 2, dg = (threadIdx.x & 3) * 16;
  const bf16* srcp = Vbuf + ((long)(j0 + jj) * 32 + b) * 1024 + h * 64 + dg;
  bf16x8 v0 = ldg8(srcp), v1 = ldg8(srcp + 8);
#pragma unroll
  for (int e = 0; e < 8; ++e) { t[jj][dg + e] = v0[e]; t[jj][dg + 8 + e] = v1[e]; }
  __syncthreads();
  const int dd = threadIdx.x >> 2, jg = (threadIdx.x & 3) * 16;
  bf16* dstp = valT + ((long)(b * 16 + h) * 64 + dd) * 512 + j0 + jg;
  bf16x8 o0, o1;
#pragma unroll
  for (int e = 0; e < 8; ++e) { o0[e] = t[jg + e][dd]; o1[e] = t[jg + 8 + e][dd]; }
  *(bf16x8*)dstp = o0;
  *(bf16x8*)(dstp + 8) = o1;
}

// ---------------- fused attention -----------------------------------------
__device__ __forceinline__ void stageKR(const char* rowbase, long strideB,
                                        bf16* stg, int tid) {
#pragma unroll
  for (int i = 0; i < 4; ++i) {
    const int slot = i * 256 + tid;
    const int row = slot >> 3;
    const int colb = ((slot << 4) & 127) ^ ((row & 7) << 4);
    gl2lds16(rowbase + (long)row * strideB + colb, (char*)stg + slot * 16);
  }
}
__device__ __forceinline__ void stageV(const char* rowbase, long strideB,
                                       bf16* stg, int tid) {
#pragma unroll
  for (int i = 0; i < 4; ++i) {
    const int slot = i * 256 + tid;
    const int row = slot >> 4;
    const int colb = ((slot << 4) & 255) ^ ((row & 7) << 4);
    gl2lds16(rowbase + (long)row * strideB + colb, (char*)stg + slot * 16);
  }
}
__device__ __forceinline__ bf16x8 rdKR(const bf16* stg, int rloc, int byteInRow) {
  const int addr = (rloc * 128 + byteInRow) ^ ((rloc & 7) << 4);
  return *(const bf16x8*)((const char*)stg + addr);
}
__device__ __forceinline__ bf16x8 rdV(const bf16* stg, int rloc, int byteInRow) {
  const int addr = (rloc * 256 + byteInRow) ^ ((rloc & 7) << 4);
  return *(const bf16x8*)((const char*)stg + addr);
}

__global__ __launch_bounds__(256, 2) void attn_kernel(
    const bf16* __restrict__ qb, const float* __restrict__ uvec,
    const float* __restrict__ vvec, const bf16* __restrict__ Kb,
    const bf16* __restrict__ rbf, const bf16* __restrict__ valT,
    bf16* __restrict__ a1out) {
  __shared__ __align__(16) bf16 s2[4][8192];   // 64KB wave-private S2/logit/P
  __shared__ __align__(16) bf16 stg[8192];     // 16KB shared staging
  const int tid = threadIdx.x;
  const int wv = tid >> 6, lane = tid & 63;
  const int l15 = lane & 15, lk = lane >> 4;
  const int bid = blockIdx.x;
  const int swzb = ((bid & 7) << 8) + (bid >> 3);  // nwg=2048, 256-chunks/XCD
  const int st = swzb & 3, h = (swzb >> 2) & 15, b = swzb >> 6;
  const int i0 = st * 64 + wv * 16;
  const long bh = (long)b * 16 + h;
  bf16* sw = s2[wv];
  const bool skipE = (st < 2);  // block-uniform masked-chunk skip

  const bf16* qp = qb + ((long)(i0 + l15) * 32 + b) * 1024 + h * 64 + lk * 8;
  bf16x8 q0 = ldg8(qp), q1 = ldg8(qp + 32);
  const float* up = uvec + h * 64 + lk * 8;
  const float* vp = vvec + h * 64 + lk * 8;
  bf16x8 a0u, a1u, a0v, a1v;
#pragma unroll
  for (int e = 0; e < 8; ++e) {
    float f0 = (float)q0[e], f1 = (float)q1[e];
    a0u[e] = (bf16)((f0 + up[e]) * 0.125f);
    a1u[e] = (bf16)((f1 + up[32 + e]) * 0.125f);
    a0v[e] = (bf16)((f0 + vp[e]) * 0.125f);
    a1v[e] = (bf16)((f1 + vp[32 + e]) * 0.125f);
  }

  // ---- Phase 1: S2 = (q+v)/8 R^T -> wave-private LDS, cols = raw index
#pragma unroll
  for (int c = 0; c < 4; ++c) {
    if (skipE && c == 0) continue;
    __syncthreads();
    stageKR((const char*)(rbf + (long)(c * 128) * 1024 + h * 64), 2048, stg, tid);
    __syncthreads();
#pragma unroll
    for (int jt = 0; jt < 8; ++jt) {
      bf16x8 b0 = rdKR(stg, jt * 16 + l15, lk * 16);
      bf16x8 b1 = rdKR(stg, jt * 16 + l15, 64 + lk * 16);
      f32x4 cc = {0.f, 0.f, 0.f, 0.f};
      cc = MFMA16(a0v, b0, cc);
      cc = MFMA16(a1v, b1, cc);
      const int jcol = (c * 8 + jt) * 16 + l15;
#pragma unroll
      for (int r = 0; r < 4; ++r) sw[sidx(lk * 4 + r, jcol)] = (bf16)cc[r];
    }
  }
  // ---- Phase 2: logits in-place (gather cols >= write col; wave-private)
#pragma unroll
  for (int c = 0; c < 4; ++c) {
    if (skipE && c == 3) continue;
    __syncthreads();
    stageKR((const char*)(Kb + ((long)(c * 128) * 32 + b) * 1024 + h * 64),
            65536, stg, tid);
    __syncthreads();
#pragma unroll
    for (int jt = 0; jt < 8; ++jt) {
      bf16x8 b0 = rdKR(stg, jt * 16 + l15, lk * 16);
      bf16x8 b1 = rdKR(stg, jt * 16 + l15, 64 + lk * 16);
      f32x4 cc = {0.f, 0.f, 0.f, 0.f};
      cc = MFMA16(a0u, b0, cc);
      cc = MFMA16(a1u, b1, cc);
      const int j = (c * 8 + jt) * 16 + l15;
      float lgv[4];
#pragma unroll
      for (int r = 0; r < 4; ++r) {
        const int i = i0 + lk * 4 + r;
        lgv[r] = (j <= i + 256)
                     ? (cc[r] + (float)sw[sidx(lk * 4 + r, j - i + 255)])
                     : -1e30f;
      }
#pragma unroll
      for (int r = 0; r < 4; ++r) sw[sidx(lk * 4 + r, j)] = (bf16)lgv[r];
    }
  }
  // ---- single-pass softmax, unnormalized; 1/sum deferred to PV epilogue
  float inv;
  {
    const int rr = lane & 15, pp = lane >> 4;
    const bool dead = skipE && (pp == 3);
    bf16x8 pk[16];
    float m = -3e38f;
    if (!dead) {
#pragma unroll
      for (int k = 0; k < 16; ++k)
        pk[k] = *(const bf16x8*)(sw + sidx(rr, pp * 128 + k * 8));
#pragma unroll
      for (int k = 0; k < 16; ++k)
#pragma unroll
        for (int e = 0; e < 8; ++e) m = fmaxf(m, (float)pk[k][e]);
    }
    m = fmaxf(m, __shfl_xor(m, 16));
    m = fmaxf(m, __shfl_xor(m, 32));
    float s = 0.f;
    if (!dead) {
#pragma unroll
      for (int k = 0; k < 16; ++k) {
        bf16x8 t;
#pragma unroll
        for (int e = 0; e < 8; ++e) {
          float ev = __expf((float)pk[k][e] - m);
          s += ev;
          t[e] = (bf16)ev;
        }
        *(bf16x8*)(sw + sidx(rr, pp * 128 + k * 8)) = t;
      }
    }
    s += __shfl_xor(s, 16);
    s += __shfl_xor(s, 32);
    inv = 1.0f / s;
  }
  // ---- Phase 3: O = (P V) * inv
  f32x4 oacc[4] = {};
  const char* vbase = (const char*)(valT + bh * 64 * 512);
#pragma unroll
  for (int c = 0; c < 4; ++c) {
    if (skipE && c == 3) continue;
    __syncthreads();
    stageV(vbase + c * 256, 1024, stg, tid);
    __syncthreads();
#pragma unroll
    for (int ksl = 0; ksl < 4; ++ksl) {
      const int ks = c * 4 + ksl;
      bf16x8 pa = *(const bf16x8*)(sw + sidx(l15, ks * 32 + lk * 8));
#pragma unroll
      for (int nt = 0; nt < 4; ++nt) {
        bf16x8 vb = rdV(stg, nt * 16 + l15, ksl * 64 + lk * 16);
        oacc[nt] = MFMA16(pa, vb, oacc[nt]);
      }
    }
  }
  float invr[4];
#pragma unroll
  for (int r = 0; r < 4; ++r) invr[r] = __shfl(inv, lk * 4 + r);
#pragma unroll
  for (int nt = 0; nt < 4; ++nt)
#pragma unroll
    for (int r = 0; r < 4; ++r) {
      const long t = (long)(i0 + lk * 4 + r) * 32 + b;
      a1out[t * 1024 + h * 64 + nt * 16 + l15] = (bf16)(oacc[nt][r] * invr[r]);
    }
}

// ---------------- generic 128x128 MFMA GEMM with fused epilogues -----------
// 3-slot ring K-loop with counted vmcnt (T4): per K-step
//   [ds_read frags T(t)] [issue stage T(t+2) -> slot (t+2)%3]
//   [setprio(1) 16xMFMA setprio(0)] [vmcnt(4) -> T(t+1) landed] [raw barrier]
// Slot indices are compile-time literals (3x-unrolled body) so alias
// analysis can disambiguate ring slots. WAR-safe: slot (t+2)%3 held T(t-1),
// whose ds_reads completed (compiler lgkmcnt before MFMA) in every wave
// before the iter-(t-1) barrier. vmcnt never drains to 0 mid-loop.
enum { EP_B16 = 0, EP_KV2 = 1, EP_GELU = 2, EP_SIGRX = 3, EP_GRU = 4 };

struct GP {
  const bf16* A0; const bf16* A1;   // A split at k=ksplit (concat-K GEMMs)
  long lda0, lda1; int ksplit; int K;
  const bf16* B;                    // [N][K] bf16 (W^T), row stride K
  const float* bias;
  const float* bg;                  // EP_SIGRX
  const float* xbuf;                // EP_SIGRX (r*x), EP_GRU (combine x), f32
  const bf16* zbuf;                 // EP_GRU (z, bf16)
  float* outf; long ldf;
  bf16* outb; long ldb;
  bf16* outb2; long ldb2;
};

#define G_STAGE(BB, K0)                                                       \
  {                                                                           \
    const int k0_ = (K0);                                                     \
    const bf16 *ag0_, *ag1_;                                                  \
    if (k0_ < p.ksplit) {                                                     \
      ag0_ = p.A0 + (m0 + srow) * p.lda0 + k0_ + skk;                         \
      ag1_ = p.A0 + (m0 + srow + 64) * p.lda0 + k0_ + skk;                    \
    } else {                                                                  \
      ag0_ = p.A1 + (m0 + srow) * p.lda1 + (k0_ - p.ksplit) + skk;            \
      ag1_ = p.A1 + (m0 + srow + 64) * p.lda1 + (k0_ - p.ksplit) + skk;       \
    }                                                                         \
    gl2lds16(ag0_, As[BB] + sdst);                                            \
    gl2lds16(ag1_, As[BB] + 64 * 32 + sdst);                                  \
    gl2lds16(Bg0 + k0_, Bs[BB] + sdst);                                       \
    gl2lds16(Bg1 + k0_, Bs[BB] + 64 * 32 + sdst);                             \
  }

#define G_SUBITER(BB, TCUR)                                                   \
  if ((TCUR) < nt) {                                                          \
    bf16x8 af[4], bfr[4];                                                     \
    _Pragma("unroll") for (int i = 0; i < 4; ++i) {                           \
      af[i] = *(const bf16x8*)(As[BB] + (wr * 64 + i * 16 + l15) * 32 + lk * 8); \
      bfr[i] = *(const bf16x8*)(Bs[BB] + (wc * 64 + i * 16 + l15) * 32 + lk * 8); \
    }                                                                         \
    if ((TCUR) + 2 < nt) G_STAGE((((BB) + 2) % 3), ((TCUR) + 2) * 32);        \
    __builtin_amdgcn_s_setprio(1);                                            \
    _Pragma("unroll") for (int i = 0; i < 4; ++i)                             \
      _Pragma("unroll") for (int j = 0; j < 4; ++j)                           \
          acc[i][j] = MFMA16(af[i], bfr[j], acc[i][j]);                       \
    __builtin_amdgcn_s_setprio(0);                                            \
    if ((TCUR) + 1 < nt) {                                                    \
      if ((TCUR) + 2 < nt)                                                    \
        asm volatile("s_waitcnt vmcnt(4)" ::: "memory");                      \
      else                                                                    \
        asm volatile("s_waitcnt vmcnt(0)" ::: "memory");                      \
      __builtin_amdgcn_s_barrier();                                           \
    }                                                                         \
  }

template <int EP>
__global__ __launch_bounds__(256, 3) void gemm_bt(GP p) {
  __shared__ __align__(16) bf16 As[3][128 * 32];
  __shared__ __align__(16) bf16 Bs[3][128 * 32];
  const int tid = threadIdx.x;
  const int lane = tid & 63;
  const int wv = tid >> 6;
  const int wr = wv >> 1, wc = wv & 1;
  const int l15 = lane & 15, lk = lane >> 4;
  const int nx = gridDim.x;
  const int nwg = nx * gridDim.y;
  const int bid = blockIdx.y * nx + blockIdx.x;
  const int qq = nwg >> 3, rr = nwg & 7, xc = bid & 7, loc = bid >> 3;
  const int swz = (xc < rr ? xc * (qq + 1) : rr * (qq + 1) + (xc - rr) * qq) + loc;
  const long n0 = (long)(swz % nx) * 128;
  const long m0 = (long)(swz / nx) * 128;
  const int srow = tid >> 2;
  const int skk = (tid & 3) * 8;
  const long sdst = (long)srow * 32 + skk;

  const bf16* Bg0 = p.B + (n0 + srow) * (long)p.K + skk;
  const bf16* Bg1 = p.B + (n0 + srow + 64) * (long)p.K + skk;

  f32x4 acc[4][4] = {};
  const int nt = p.K >> 5;

  // prologue: T0 -> slot0, T1 -> slot1; wait T0 landed (outstanding <= T1's 4)
  G_STAGE(0, 0);
  G_STAGE(1, 32);
  asm volatile("s_waitcnt vmcnt(4)" ::: "memory");
  __builtin_amdgcn_s_barrier();

#pragma unroll 1
  for (int t = 0; t < nt; t += 3) {
    G_SUBITER(0, t);
    G_SUBITER(1, t + 1);
    G_SUBITER(2, t + 2);
  }

#pragma unroll
  for (int i = 0; i < 4; ++i) {
#pragma unroll
    for (int j = 0; j < 4; ++j) {
#pragma unroll
      for (int r = 0; r < 4; ++r) {
        const long row = m0 + wr * 64 + i * 16 + lk * 4 + r;
        const long col = n0 + wc * 64 + j * 16 + l15;
        float v = acc[i][j][r];
        if constexpr (EP == EP_B16) {
          v += p.bias[col];
          p.outb[row * p.ldb + col] = (bf16)v;
        } else if constexpr (EP == EP_KV2) {
          v += p.bias[col];
          if (col < 1024) p.outb[row * p.ldb + col] = (bf16)v;          // K
          else p.outb2[row * p.ldb2 + (col - 1024)] = (bf16)v;          // V
        } else if constexpr (EP == EP_GELU) {
          v += p.bias[col];
          float g = 0.5f * v * (1.0f + erff(v * 0.70710678118654752f));
          p.outb[row * p.ldb + col] = (bf16)g;
        } else if constexpr (EP == EP_SIGRX) {
          if (col >= 1024) {
            float sg = 1.0f / (1.0f + __expf(-(v - p.bg[col - 1024])));
            p.outb2[row * p.ldb2 + (col - 1024)] = (bf16)sg;            // z
          } else {
            float sg = 1.0f / (1.0f + __expf(-v));
            p.outb[row * p.ldb + col] = (bf16)(sg * p.xbuf[row * 1024 + col]);  // r*x
          }
        } else if constexpr (EP == EP_GRU) {
          float z = (float)p.zbuf[row * 1024 + col];
          float x = p.xbuf[row * 1024 + col];
          float vc = fminf(fmaxf(v, -15.f), 15.f);
          float e2 = __expf(2.0f * vc);
          float th = (e2 - 1.0f) / (e2 + 1.0f);
          float o = (1.0f - z) * x + z * th;
          p.outf[row * p.ldf + col] = o;
          if (p.outb != nullptr) p.outb[row * p.ldb + col] = (bf16)o;
        }
      }
    }
  }
}

// ---------------------------------------------------------------------------
extern "C" void kernel_launch(void* const* d_in, const int* in_sizes, int n_in,
                              void* d_out, int out_size, void* d_ws, size_t ws_size,
                              hipStream_t stream) {
  const float* inputs = (const float*)d_in[0];
  const float* posemb = (const float*)d_in[1];
  const float* u_in = (const float*)d_in[2];
  const float* v_in = (const float*)d_in[3];
  const float* memory = (const float*)d_in[4];
  // d_in[5] = mask: analytic (unmasked iff j <= i+256), not read.
  const float* ln1_g = (const float*)d_in[6];
  const float* ln1_b = (const float*)d_in[7];
  const float* ln2_g = (const float*)d_in[8];
  const float* ln2_b = (const float*)d_in[9];
  const float* W_kv = (const float*)d_in[10];
  const float* b_kv = (const float*)d_in[11];
  const float* W_q = (const float*)d_in[12];
  const float* b_q = (const float*)d_in[13];
  const float* W_pos = (const float*)d_in[14];
  const float* b_pos = (const float*)d_in[15];
  const float* W_o = (const float*)d_in[16];
  const float* b_o = (const float*)d_in[17];
  const float* g1_Wr = (const float*)d_in[18];
  const float* g1_Ur = (const float*)d_in[19];
  const float* g1_Wz = (const float*)d_in[20];
  const float* g1_Uz = (const float*)d_in[21];
  const float* g1_Wg = (const float*)d_in[22];
  const float* g1_Ug = (const float*)d_in[23];
  const float* g1_bg = (const float*)d_in[24];
  const float* g2_Wr = (const float*)d_in[25];
  const float* g2_Ur = (const float*)d_in[26];
  const float* g2_Wz = (const float*)d_in[27];
  const float* g2_Uz = (const float*)d_in[28];
  const float* g2_Wg = (const float*)d_in[29];
  const float* g2_Ug = (const float*)d_in[30];
  const float* g2_bg = (const float*)d_in[31];
  const float* W_m1 = (const float*)d_in[32];
  const float* b_m1 = (const float*)d_in[33];
  const float* W_m2 = (const float*)d_in[34];
  const float* b_m2 = (const float*)d_in[35];
  float* out = (float*)d_out;
  float* o1 = out;  // f32 o1 parked in d_out (fully rewritten s11, read 12/15/16)

  const size_t MB = 1024UL * 1024UL;
  const size_t sizeB = 154 * MB;
  const size_t sizeA = 196 * MB;
  const bool A = (ws_size >= sizeA);
  if (!A && ws_size < sizeB) {  // canary: absmax ~3.4e38 => ws too small
    hipMemsetAsync(d_out, 0x7F, 256, stream);
    return;
  }

  char* w = (char*)d_ws;
  size_t off = 0;
  auto take = [&](size_t bytes) { char* p = w + off; off += bytes; return p; };
  char* RW = take(A ? 50 * MB : 8 * MB);
  bf16* posbf = (bf16*)take(1 * MB);
  bf16* rbf = (bf16*)take(1 * MB);
  char* R3 = take(32 * MB);   // x1(1-4) | valT(7-8) | y1@0(9-11), x2@16M(12-13) | m2@0(14-16)
  char* R45 = take(64 * MB);  // Kbuf@0 + Vbuf@32M (4-8) | mh 64MB (13-14)
  char* R6 = take(16 * MB);   // xb16(1-10) | o1b(11-16)
  char* R7 = take(16 * MB);   // qb(5-8) | rx(10-16)
  char* R8 = take(16 * MB);   // a1b(8-9) | z1b(10-16)

  bf16* WT = (bf16*)RW;
  bf16* WkvT  = A ? (bf16*)(RW + 0 * MB)  : WT;
  bf16* WqT   = A ? (bf16*)(RW + 4 * MB)  : WT;
  bf16* WposT = A ? (bf16*)(RW + 6 * MB)  : WT;
  bf16* WoT   = A ? (bf16*)(RW + 8 * MB)  : WT;
  bf16* G1rz  = A ? (bf16*)(RW + 10 * MB) : WT;
  bf16* G1g   = A ? (bf16*)(RW + 18 * MB) : WT;
  bf16* Wm1T  = A ? (bf16*)(RW + 22 * MB) : WT;
  bf16* Wm2T  = A ? (bf16*)(RW + 30 * MB) : WT;
  bf16* G2rz  = A ? (bf16*)(RW + 38 * MB) : WT;
  bf16* G2g   = A ? (bf16*)(RW + 46 * MB) : WT;

  bf16* x1 = (bf16*)R3;
  bf16* valT = (bf16*)R3;
  bf16* y1 = (bf16*)R3;
  bf16* x2 = (bf16*)(R3 + 16 * MB);
  bf16* m2 = (bf16*)R3;
  bf16* Kbuf = (bf16*)R45;
  bf16* Vbuf = (bf16*)(R45 + 32 * MB);
  bf16* mh = (bf16*)R45;
  bf16* xb16 = (bf16*)R6;
  bf16* o1b = (bf16*)R6;
  bf16* qb = (bf16*)R7;
  bf16* rx = (bf16*)R7;
  bf16* a1b = (bf16*)R8;
  bf16* z1b = (bf16*)R8;

  dim3 blk(256);
  auto addT = [](TPack& p, const float* src, bf16* dst, int K, int N, int ldd) {
    TDesc& d = p.d[p.nd++];
    d.src = src; d.dst = dst; d.N = N; d.ldd = ldd; d.start = p.total;
    p.total += (N / 64) * (K / 64);
  };
  auto runT = [&](TPack& p) {
    wtrans_multi<<<dim3(p.total), blk, 0, stream>>>(p);
  };
  auto T_kv = [&](TPack& p) { addT(p, W_kv, WkvT, 1024, 2048, 1024); };
  auto T_q = [&](TPack& p) { addT(p, W_q, WqT, 1024, 1024, 1024); };
  auto T_pos = [&](TPack& p) { addT(p, W_pos, WposT, 1024, 1024, 1024); };
  auto T_o = [&](TPack& p) { addT(p, W_o, WoT, 1024, 1024, 1024); };
  auto T_g1rz = [&](TPack& p) {
    addT(p, g1_Wr, G1rz, 1024, 1024, 2048);
    addT(p, g1_Ur, G1rz + 1024, 1024, 1024, 2048);
    addT(p, g1_Wz, G1rz + 1024L * 2048, 1024, 1024, 2048);
    addT(p, g1_Uz, G1rz + 1024L * 2048 + 1024, 1024, 1024, 2048);
  };
  auto T_g1g = [&](TPack& p) {
    addT(p, g1_Wg, G1g, 1024, 1024, 2048);
    addT(p, g1_Ug, G1g + 1024, 1024, 1024, 2048);
  };
  auto T_m1 = [&](TPack& p) { addT(p, W_m1, Wm1T, 1024, 4096, 1024); };
  auto T_m2 = [&](TPack& p) { addT(p, W_m2, Wm2T, 4096, 1024, 4096); };
  auto T_g2rz = [&](TPack& p) {
    addT(p, g2_Wr, G2rz, 1024, 1024, 2048);
    addT(p, g2_Ur, G2rz + 1024, 1024, 1024, 2048);
    addT(p, g2_Wz, G2rz + 1024L * 2048, 1024, 1024, 2048);
    addT(p, g2_Uz, G2rz + 1024L * 2048 + 1024, 1024, 1024, 2048);
  };
  auto T_g2g = [&](TPack& p) {
    addT(p, g2_Wg, G2g, 1024, 1024, 2048);
    addT(p, g2_Ug, G2g + 1024, 1024, 1024, 2048);
  };
  auto maybeT = [&](auto builder) {
    if (!A) { TPack p{}; builder(p); runT(p); }
  };

  if (A) {  // one batched transpose for all 18 weights
    TPack p{};
    T_kv(p); T_q(p); T_pos(p); T_o(p); T_g1rz(p); T_g1g(p);
    T_m1(p); T_m2(p); T_g2rz(p); T_g2g(p);
    runT(p);
  }

  // 1. LN1 over [memory; inputs] -> x1; raw inputs bf16 -> xb16
  ln_kernel<<<16384, blk, 0, stream>>>(memory, inputs, ln1_g, ln1_b, x1, 1024,
                                       xb16, 1024, 8192);
  // 2. pos_embedding -> bf16
  cvt_bf16_kernel<<<512, blk, 0, stream>>>(posemb, posbf);

  // 4. kv GEMM: K -> Kbuf, V -> Vbuf (both coalesced)
  maybeT(T_kv);
  {
    GP p{};
    p.A0 = p.A1 = x1; p.lda0 = p.lda1 = 1024; p.ksplit = 1 << 30; p.K = 1024;
    p.B = WkvT; p.bias = b_kv; p.outb = Kbuf; p.ldb = 1024;
    p.outb2 = Vbuf; p.ldb2 = 1024;
    gemm_bt<EP_KV2><<<dim3(16, 128), blk, 0, stream>>>(p);
  }
  // 5. q = inputs @ W_q + b_q -> qb (u/v added inside attention)
  maybeT(T_q);
  {
    GP p{};
    p.A0 = p.A1 = xb16; p.lda0 = p.lda1 = 1024; p.ksplit = 1 << 30; p.K = 1024;
    p.B = WqT; p.bias = b_q; p.outb = qb; p.ldb = 1024;
    gemm_bt<EP_B16><<<dim3(8, 64), blk, 0, stream>>>(p);
  }
  // 6. r = pos_embedding @ W_pos + b_pos -> rbf
  maybeT(T_pos);
  {
    GP p{};
    p.A0 = p.A1 = posbf; p.lda0 = p.lda1 = 1024; p.ksplit = 1 << 30; p.K = 1024;
    p.B = WposT; p.bias = b_pos; p.outb = rbf; p.ldb = 1024;
    gemm_bt<EP_B16><<<dim3(8, 4), blk, 0, stream>>>(p);
  }
  // 7. V transpose (x1 dead; valT overlays R3)
  valt_kernel<<<dim3(32, 16, 8), blk, 0, stream>>>(Vbuf, valT);
  // 8. fused attention -> a1b
  attn_kernel<<<dim3(2048), blk, 0, stream>>>(qb, u_in, v_in, Kbuf, rbf, valT, a1b);
  // 9. y1 = gelu(a1 @ W_o + b_o)
  maybeT(T_o);
  {
    GP p{};
    p.A0 = p.A1 = a1b; p.lda0 = p.lda1 = 1024; p.ksplit = 1 << 30; p.K = 1024;
    p.B = WoT; p.bias = b_o; p.outb = y1; p.ldb = 1024;
    gemm_bt<EP_GELU><<<dim3(8, 64), blk, 0, stream>>>(p);
  }
  // 10. gate1 r/z: [y1|x] @ [Wr Ur; Wz Uz]; r*x -> rx, z -> z1b
  maybeT(T_g1rz);
  {
    GP p{};
    p.A0 = y1; p.lda0 = 1024; p.A1 = xb16; p.lda1 = 1024; p.ksplit = 1024; p.K = 2048;
    p.B = G1rz; p.bg = g1_bg; p.xbuf = inputs;
    p.outb = rx; p.ldb = 1024; p.outb2 = z1b; p.ldb2 = 1024;
    gemm_bt<EP_SIGRX><<<dim3(16, 64), blk, 0, stream>>>(p);
  }
  // 11. gate1 h + combine: o1 = (1-z)*x + z*tanh([y1|rx] @ [Wg;Ug])
  maybeT(T_g1g);
  {
    GP p{};
    p.A0 = y1; p.lda0 = 1024; p.A1 = rx; p.lda1 = 1024; p.ksplit = 1024; p.K = 2048;
    p.B = G1g; p.zbuf = z1b; p.xbuf = inputs;
    p.outf = o1; p.ldf = 1024; p.outb = o1b; p.ldb = 1024;
    gemm_bt<EP_GRU><<<dim3(8, 64), blk, 0, stream>>>(p);
  }
  // 12. LN2(o1) -> x2
  ln_kernel<<<8192, blk, 0, stream>>>(o1, nullptr, ln2_g, ln2_b, x2, 1024,
                                      nullptr, 0, 1 << 30);
  // 13. mh = gelu(x2 @ W_m1 + b_m1)
  maybeT(T_m1);
  {
    GP p{};
    p.A0 = p.A1 = x2; p.lda0 = p.lda1 = 1024; p.ksplit = 1 << 30; p.K = 1024;
    p.B = Wm1T; p.bias = b_m1; p.outb = mh; p.ldb = 4096;
    gemm_bt<EP_GELU><<<dim3(32, 64), blk, 0, stream>>>(p);
  }
  // 14. m2 = gelu(mh @ W_m2 + b_m2)
  maybeT(T_m2);
  {
    GP p{};
    p.A0 = p.A1 = mh; p.lda0 = p.lda1 = 4096; p.ksplit = 1 << 30; p.K = 4096;
    p.B = Wm2T; p.bias = b_m2; p.outb = m2; p.ldb = 1024;
    gemm_bt<EP_GELU><<<dim3(8, 64), blk, 0, stream>>>(p);
  }
  // 15. gate2 r/z: [m2|o1b]; r*o1 -> rx, z -> z1b
  maybeT(T_g2rz);
  {
    GP p{};
    p.A0 = m2; p.lda0 = 1024; p.A1 = o1b; p.lda1 = 1024; p.ksplit = 1024; p.K = 2048;
    p.B = G2rz; p.bg = g2_bg; p.xbuf = o1;
    p.outb = rx; p.ldb = 1024; p.outb2 = z1b; p.ldb2 = 1024;
    gemm_bt<EP_SIGRX><<<dim3(16, 64), blk, 0, stream>>>(p);
  }
  // 16. gate2 h + combine -> d_out (in-place over o1: own-element read/write)
  maybeT(T_g2g);
  {
    GP p{};
    p.A0 = m2; p.lda0 = 1024; p.A1 = rx; p.lda1 = 1024; p.ksplit = 1024; p.K = 2048;
    p.B = G2g; p.zbuf = z1b; p.xbuf = o1;
    p.outf = out; p.ldf = 1024; p.outb = nullptr;
    gemm_bt<EP_GRU><<<dim3(8, 64), blk, 0, stream>>>(p);
  }
}

// Round 9
// 849.261 us; speedup vs baseline: 1.0411x; 1.0061x over previous
//
#include <hip/hip_runtime.h>
#include <cstdint>

// ---------------------------------------------------------------------------
// GatedTransformerXLLayer on MI355X (gfx950).
// D=1024, H=16, HD=64, FF=4096, CUR=256, MEM=256, BS=32, FULL=512.
// bf16 MFMA (16x16x32); 128x128 GEMM with 3-slot ring LDS + counted
// s_waitcnt vmcnt(4) + raw s_barrier (T4) + XCD swizzle + setprio (T5)
// + T2 LDS XOR-swizzle (linear gl2lds dest, inverse-swizzled global
// source, swizzled ds_read: 8-way -> 2-way bank conflict).
// Fused attention with staged K/R/V, pre-scaled q, chunk skipping,
// single-pass __expf softmax with deferred 1/sum.
// ---------------------------------------------------------------------------

typedef __bf16 bf16;
typedef bf16 bf16x4 __attribute__((ext_vector_type(4)));
typedef bf16 bf16x8 __attribute__((ext_vector_type(8)));
typedef float f32x4 __attribute__((ext_vector_type(4)));

#define MFMA16(a, b, c) __builtin_amdgcn_mfma_f32_16x16x32_bf16((a), (b), (c), 0, 0, 0)

__device__ __forceinline__ void gl2lds16(const void* g, void* l) {
  __builtin_amdgcn_global_load_lds(
      (const __attribute__((address_space(1))) unsigned int*)g,
      (__attribute__((address_space(3))) unsigned int*)l, 16, 0, 0);
}

__device__ __forceinline__ bf16x8 ldg8(const bf16* p) { return *(const bf16x8*)p; }

// XOR-swizzled index into a [16][512] bf16 wave-slice (u16 units).
__device__ __forceinline__ int sidx(int row, int col) {
  return (row * 512 + col) ^ ((row & 7) << 3);
}

// ---------------- LayerNorm (one row per block, 256 thr x float4) ----------
__global__ __launch_bounds__(256) void ln_kernel(
    const float* __restrict__ src0, const float* __restrict__ src1,
    const float* __restrict__ gam, const float* __restrict__ bet,
    bf16* __restrict__ out, long ldo,
    bf16* __restrict__ raw, long ldraw, int rawstart) {
  const int row = blockIdx.x;
  const int tid = threadIdx.x;
  const float* src = (src1 != nullptr && row >= rawstart)
                         ? (src1 + (long)(row - rawstart) * 1024)
                         : (src0 + (long)row * 1024);
  float4 v = ((const float4*)src)[tid];
  float s = v.x + v.y + v.z + v.w;
#pragma unroll
  for (int o = 32; o > 0; o >>= 1) s += __shfl_down(s, o);
  __shared__ float red[8];
  const int wv = tid >> 6, lane = tid & 63;
  if (lane == 0) red[wv] = s;
  __syncthreads();
  float mean = (red[0] + red[1] + red[2] + red[3]) * (1.0f / 1024.0f);
  float dx = v.x - mean, dy = v.y - mean, dz = v.z - mean, dw = v.w - mean;
  float ss = dx * dx + dy * dy + dz * dz + dw * dw;
#pragma unroll
  for (int o = 32; o > 0; o >>= 1) ss += __shfl_down(ss, o);
  if (lane == 0) red[4 + wv] = ss;
  __syncthreads();
  float var = (red[4] + red[5] + red[6] + red[7]) * (1.0f / 1024.0f);
  float rstd = rsqrtf(var + 1e-5f);
  int c = tid * 4;
  float4 g4 = ((const float4*)gam)[tid];
  float4 b4 = ((const float4*)bet)[tid];
  bf16x4 o4;
  o4[0] = (bf16)(dx * rstd * g4.x + b4.x);
  o4[1] = (bf16)(dy * rstd * g4.y + b4.y);
  o4[2] = (bf16)(dz * rstd * g4.z + b4.z);
  o4[3] = (bf16)(dw * rstd * g4.w + b4.w);
  *(bf16x4*)(out + (long)row * ldo + c) = o4;
  if (raw != nullptr && row >= rawstart) {
    bf16x4 r4;
    r4[0] = (bf16)v.x; r4[1] = (bf16)v.y; r4[2] = (bf16)v.z; r4[3] = (bf16)v.w;
    *(bf16x4*)(raw + (long)(row - rawstart) * ldraw + c) = r4;
  }
}

// ---------------- fp32 -> bf16 convert -------------------------------------
__global__ __launch_bounds__(256) void cvt_bf16_kernel(const float* __restrict__ s,
                                                       bf16* __restrict__ d) {
  long i = ((long)blockIdx.x * 256 + threadIdx.x) * 4;
  float4 v = *(const float4*)(s + i);
  bf16x4 o;
  o[0] = (bf16)v.x; o[1] = (bf16)v.y; o[2] = (bf16)v.z; o[3] = (bf16)v.w;
  *(bf16x4*)(d + i) = o;
}

// ---------------- batched weight transpose+convert -------------------------
struct TDesc { const float* src; bf16* dst; int N; int ldd; int start; };
struct TPack { TDesc d[18]; int nd; int total; };

__global__ __launch_bounds__(256) void wtrans_multi(TPack p) {
  __shared__ bf16 t[64][66];
  const int tile = blockIdx.x;
  int wi = 0;
#pragma unroll 1
  for (int i = 1; i < p.nd; ++i)
    if (tile >= p.d[i].start) wi = i;
  const float* src = p.d[wi].src;
  bf16* dst = p.d[wi].dst;
  const int N = p.d[wi].N;
  const long ldd = p.d[wi].ldd;
  const int local = tile - p.d[wi].start;
  const int tiles_x = N >> 6;
  const int n0 = (local % tiles_x) * 64, k0 = (local / tiles_x) * 64;
  const int tx = threadIdx.x & 63, ty = threadIdx.x >> 6;
#pragma unroll
  for (int i = 0; i < 64; i += 4)
    t[ty + i][tx] = (bf16)src[(long)(k0 + ty + i) * N + n0 + tx];
  __syncthreads();
#pragma unroll
  for (int i = 0; i < 64; i += 4)
    dst[(long)(n0 + ty + i) * ldd + k0 + tx] = t[tx][ty + i];
}

// ---------------- V transpose: Vbuf[t][1024] -> valT[(b*16+h)*64+d][j] -----
__global__ __launch_bounds__(256) void valt_kernel(const bf16* __restrict__ Vbuf,
                                                   bf16* __restrict__ valT) {
  __shared__ bf16 t[64][66];
  const int b = blockIdx.x, h = blockIdx.y, j0 = blockIdx.z * 64;
  const int jj = threadIdx.x >> 2, dg = (threadIdx.x & 3) * 16;
  const bf16* srcp = Vbuf + ((long)(j0 + jj) * 32 + b) * 1024 + h * 64 + dg;
  bf16x8 v0 = ldg8(srcp), v1 = ldg8(srcp + 8);
#pragma unroll
  for (int e = 0; e < 8; ++e) { t[jj][dg + e] = v0[e]; t[jj][dg + 8 + e] = v1[e]; }
  __syncthreads();
  const int dd = threadIdx.x >> 2, jg = (threadIdx.x & 3) * 16;
  bf16* dstp = valT + ((long)(b * 16 + h) * 64 + dd) * 512 + j0 + jg;
  bf16x8 o0, o1;
#pragma unroll
  for (int e = 0; e < 8; ++e) { o0[e] = t[jg + e][dd]; o1[e] = t[jg + 8 + e][dd]; }
  *(bf16x8*)dstp = o0;
  *(bf16x8*)(dstp + 8) = o1;
}

// ---------------- fused attention -----------------------------------------
__device__ __forceinline__ void stageKR(const char* rowbase, long strideB,
                                        bf16* stg, int tid) {
#pragma unroll
  for (int i = 0; i < 4; ++i) {
    const int slot = i * 256 + tid;
    const int row = slot >> 3;
    const int colb = ((slot << 4) & 127) ^ ((row & 7) << 4);
    gl2lds16(rowbase + (long)row * strideB + colb, (char*)stg + slot * 16);
  }
}
__device__ __forceinline__ void stageV(const char* rowbase, long strideB,
                                       bf16* stg, int tid) {
#pragma unroll
  for (int i = 0; i < 4; ++i) {
    const int slot = i * 256 + tid;
    const int row = slot >> 4;
    const int colb = ((slot << 4) & 255) ^ ((row & 7) << 4);
    gl2lds16(rowbase + (long)row * strideB + colb, (char*)stg + slot * 16);
  }
}
__device__ __forceinline__ bf16x8 rdKR(const bf16* stg, int rloc, int byteInRow) {
  const int addr = (rloc * 128 + byteInRow) ^ ((rloc & 7) << 4);
  return *(const bf16x8*)((const char*)stg + addr);
}
__device__ __forceinline__ bf16x8 rdV(const bf16* stg, int rloc, int byteInRow) {
  const int addr = (rloc * 256 + byteInRow) ^ ((rloc & 7) << 4);
  return *(const bf16x8*)((const char*)stg + addr);
}

__global__ __launch_bounds__(256, 2) void attn_kernel(
    const bf16* __restrict__ qb, const float* __restrict__ uvec,
    const float* __restrict__ vvec, const bf16* __restrict__ Kb,
    const bf16* __restrict__ rbf, const bf16* __restrict__ valT,
    bf16* __restrict__ a1out) {
  __shared__ __align__(16) bf16 s2[4][8192];   // 64KB wave-private S2/logit/P
  __shared__ __align__(16) bf16 stg[8192];     // 16KB shared staging
  const int tid = threadIdx.x;
  const int wv = tid >> 6, lane = tid & 63;
  const int l15 = lane & 15, lk = lane >> 4;
  const int bid = blockIdx.x;
  const int swzb = ((bid & 7) << 8) + (bid >> 3);  // nwg=2048, 256-chunks/XCD
  const int st = swzb & 3, h = (swzb >> 2) & 15, b = swzb >> 6;
  const int i0 = st * 64 + wv * 16;
  const long bh = (long)b * 16 + h;
  bf16* sw = s2[wv];
  const bool skipE = (st < 2);  // block-uniform masked-chunk skip

  const bf16* qp = qb + ((long)(i0 + l15) * 32 + b) * 1024 + h * 64 + lk * 8;
  bf16x8 q0 = ldg8(qp), q1 = ldg8(qp + 32);
  const float* up = uvec + h * 64 + lk * 8;
  const float* vp = vvec + h * 64 + lk * 8;
  bf16x8 a0u, a1u, a0v, a1v;
#pragma unroll
  for (int e = 0; e < 8; ++e) {
    float f0 = (float)q0[e], f1 = (float)q1[e];
    a0u[e] = (bf16)((f0 + up[e]) * 0.125f);
    a1u[e] = (bf16)((f1 + up[32 + e]) * 0.125f);
    a0v[e] = (bf16)((f0 + vp[e]) * 0.125f);
    a1v[e] = (bf16)((f1 + vp[32 + e]) * 0.125f);
  }

  // ---- Phase 1: S2 = (q+v)/8 R^T -> wave-private LDS, cols = raw index
#pragma unroll
  for (int c = 0; c < 4; ++c) {
    if (skipE && c == 0) continue;
    __syncthreads();
    stageKR((const char*)(rbf + (long)(c * 128) * 1024 + h * 64), 2048, stg, tid);
    __syncthreads();
#pragma unroll
    for (int jt = 0; jt < 8; ++jt) {
      bf16x8 b0 = rdKR(stg, jt * 16 + l15, lk * 16);
      bf16x8 b1 = rdKR(stg, jt * 16 + l15, 64 + lk * 16);
      f32x4 cc = {0.f, 0.f, 0.f, 0.f};
      cc = MFMA16(a0v, b0, cc);
      cc = MFMA16(a1v, b1, cc);
      const int jcol = (c * 8 + jt) * 16 + l15;
#pragma unroll
      for (int r = 0; r < 4; ++r) sw[sidx(lk * 4 + r, jcol)] = (bf16)cc[r];
    }
  }
  // ---- Phase 2: logits in-place (gather cols >= write col; wave-private)
#pragma unroll
  for (int c = 0; c < 4; ++c) {
    if (skipE && c == 3) continue;
    __syncthreads();
    stageKR((const char*)(Kb + ((long)(c * 128) * 32 + b) * 1024 + h * 64),
            65536, stg, tid);
    __syncthreads();
#pragma unroll
    for (int jt = 0; jt < 8; ++jt) {
      bf16x8 b0 = rdKR(stg, jt * 16 + l15, lk * 16);
      bf16x8 b1 = rdKR(stg, jt * 16 + l15, 64 + lk * 16);
      f32x4 cc = {0.f, 0.f, 0.f, 0.f};
      cc = MFMA16(a0u, b0, cc);
      cc = MFMA16(a1u, b1, cc);
      const int j = (c * 8 + jt) * 16 + l15;
      float lgv[4];
#pragma unroll
      for (int r = 0; r < 4; ++r) {
        const int i = i0 + lk * 4 + r;
        lgv[r] = (j <= i + 256)
                     ? (cc[r] + (float)sw[sidx(lk * 4 + r, j - i + 255)])
                     : -1e30f;
      }
#pragma unroll
      for (int r = 0; r < 4; ++r) sw[sidx(lk * 4 + r, j)] = (bf16)lgv[r];
    }
  }
  // ---- single-pass softmax, unnormalized; 1/sum deferred to PV epilogue
  float inv;
  {
    const int rr = lane & 15, pp = lane >> 4;
    const bool dead = skipE && (pp == 3);
    bf16x8 pk[16];
    float m = -3e38f;
    if (!dead) {
#pragma unroll
      for (int k = 0; k < 16; ++k)
        pk[k] = *(const bf16x8*)(sw + sidx(rr, pp * 128 + k * 8));
#pragma unroll
      for (int k = 0; k < 16; ++k)
#pragma unroll
        for (int e = 0; e < 8; ++e) m = fmaxf(m, (float)pk[k][e]);
    }
    m = fmaxf(m, __shfl_xor(m, 16));
    m = fmaxf(m, __shfl_xor(m, 32));
    float s = 0.f;
    if (!dead) {
#pragma unroll
      for (int k = 0; k < 16; ++k) {
        bf16x8 t;
#pragma unroll
        for (int e = 0; e < 8; ++e) {
          float ev = __expf((float)pk[k][e] - m);
          s += ev;
          t[e] = (bf16)ev;
        }
        *(bf16x8*)(sw + sidx(rr, pp * 128 + k * 8)) = t;
      }
    }
    s += __shfl_xor(s, 16);
    s += __shfl_xor(s, 32);
    inv = 1.0f / s;
  }
  // ---- Phase 3: O = (P V) * inv
  f32x4 oacc[4] = {};
  const char* vbase = (const char*)(valT + bh * 64 * 512);
#pragma unroll
  for (int c = 0; c < 4; ++c) {
    if (skipE && c == 3) continue;
    __syncthreads();
    stageV(vbase + c * 256, 1024, stg, tid);
    __syncthreads();
#pragma unroll
    for (int ksl = 0; ksl < 4; ++ksl) {
      const int ks = c * 4 + ksl;
      bf16x8 pa = *(const bf16x8*)(sw + sidx(l15, ks * 32 + lk * 8));
#pragma unroll
      for (int nt = 0; nt < 4; ++nt) {
        bf16x8 vb = rdV(stg, nt * 16 + l15, ksl * 64 + lk * 16);
        oacc[nt] = MFMA16(pa, vb, oacc[nt]);
      }
    }
  }
  float invr[4];
#pragma unroll
  for (int r = 0; r < 4; ++r) invr[r] = __shfl(inv, lk * 4 + r);
#pragma unroll
  for (int nt = 0; nt < 4; ++nt)
#pragma unroll
    for (int r = 0; r < 4; ++r) {
      const long t = (long)(i0 + lk * 4 + r) * 32 + b;
      a1out[t * 1024 + h * 64 + nt * 16 + l15] = (bf16)(oacc[nt][r] * invr[r]);
    }
}

// ---------------- generic 128x128 MFMA GEMM with fused epilogues -----------
// 3-slot ring (T4 counted vmcnt) + T2 XOR swizzle:
//   stage: lane tid loads k-chunk ((tid&3)^((tid>>3)&3)) of its row into the
//          LINEAR gl2lds dest (LDS[row*64B + (tid&3)*16B]) -> LDS holds
//          LDS[row][c] = G[row][c ^ s(row)], s(row) = (row>>1)&3.
//   read:  chunk offset (lk ^ ((l15>>1)&3))*8 -> content = G[row][lk]; the
//          16 l15-lanes hit all 8 bank-groups exactly twice (2-way = free).
enum { EP_B16 = 0, EP_KV2 = 1, EP_GELU = 2, EP_SIGRX = 3, EP_GRU = 4 };

struct GP {
  const bf16* A0; const bf16* A1;   // A split at k=ksplit (concat-K GEMMs)
  long lda0, lda1; int ksplit; int K;
  const bf16* B;                    // [N][K] bf16 (W^T), row stride K
  const float* bias;
  const float* bg;                  // EP_SIGRX
  const float* xbuf;                // EP_SIGRX (r*x), EP_GRU (combine x), f32
  const bf16* zbuf;                 // EP_GRU (z, bf16)
  float* outf; long ldf;
  bf16* outb; long ldb;
  bf16* outb2; long ldb2;
};

#define G_STAGE(BB, K0)                                                       \
  {                                                                           \
    const int k0_ = (K0);                                                     \
    const bf16 *ag0_, *ag1_;                                                  \
    if (k0_ < p.ksplit) {                                                     \
      ag0_ = p.A0 + (m0 + srow) * p.lda0 + k0_ + skkx;                        \
      ag1_ = p.A0 + (m0 + srow + 64) * p.lda0 + k0_ + skkx;                   \
    } else {                                                                  \
      ag0_ = p.A1 + (m0 + srow) * p.lda1 + (k0_ - p.ksplit) + skkx;           \
      ag1_ = p.A1 + (m0 + srow + 64) * p.lda1 + (k0_ - p.ksplit) + skkx;      \
    }                                                                         \
    gl2lds16(ag0_, As[BB] + sdst);                                            \
    gl2lds16(ag1_, As[BB] + 64 * 32 + sdst);                                  \
    gl2lds16(Bg0 + k0_, Bs[BB] + sdst);                                       \
    gl2lds16(Bg1 + k0_, Bs[BB] + 64 * 32 + sdst);                             \
  }

#define G_SUBITER(BB, TCUR)                                                   \
  if ((TCUR) < nt) {                                                          \
    bf16x8 af[4], bfr[4];                                                     \
    _Pragma("unroll") for (int i = 0; i < 4; ++i) {                           \
      af[i] = *(const bf16x8*)(As[BB] + (wr * 64 + i * 16 + l15) * 32 + lkx8); \
      bfr[i] = *(const bf16x8*)(Bs[BB] + (wc * 64 + i * 16 + l15) * 32 + lkx8); \
    }                                                                         \
    if ((TCUR) + 2 < nt) G_STAGE((((BB) + 2) % 3), ((TCUR) + 2) * 32);        \
    __builtin_amdgcn_s_setprio(1);                                            \
    _Pragma("unroll") for (int i = 0; i < 4; ++i)                             \
      _Pragma("unroll") for (int j = 0; j < 4; ++j)                           \
          acc[i][j] = MFMA16(af[i], bfr[j], acc[i][j]);                       \
    __builtin_amdgcn_s_setprio(0);                                            \
    if ((TCUR) + 1 < nt) {                                                    \
      if ((TCUR) + 2 < nt)                                                    \
        asm volatile("s_waitcnt vmcnt(4)" ::: "memory");                      \
      else                                                                    \
        asm volatile("s_waitcnt vmcnt(0)" ::: "memory");                      \
      __builtin_amdgcn_s_barrier();                                           \
    }                                                                         \
  }

template <int EP>
__global__ __launch_bounds__(256, 3) void gemm_bt(GP p) {
  __shared__ __align__(16) bf16 As[3][128 * 32];
  __shared__ __align__(16) bf16 Bs[3][128 * 32];
  const int tid = threadIdx.x;
  const int lane = tid & 63;
  const int wv = tid >> 6;
  const int wr = wv >> 1, wc = wv & 1;
  const int l15 = lane & 15, lk = lane >> 4;
  const int lkx8 = (lk ^ ((l15 >> 1) & 3)) * 8;   // T2 swizzled read chunk
  const int nx = gridDim.x;
  const int nwg = nx * gridDim.y;
  const int bid = blockIdx.y * nx + blockIdx.x;
  const int qq = nwg >> 3, rr = nwg & 7, xc = bid & 7, loc = bid >> 3;
  const int swz = (xc < rr ? xc * (qq + 1) : rr * (qq + 1) + (xc - rr) * qq) + loc;
  const long n0 = (long)(swz % nx) * 128;
  const long m0 = (long)(swz / nx) * 128;
  const int srow = tid >> 2;
  const int skk = (tid & 3) * 8;
  const int skkx = ((tid & 3) ^ ((tid >> 3) & 3)) * 8;  // inverse-swz source
  const long sdst = (long)srow * 32 + skk;              // linear gl2lds dest

  const bf16* Bg0 = p.B + (n0 + srow) * (long)p.K + skkx;
  const bf16* Bg1 = p.B + (n0 + srow + 64) * (long)p.K + skkx;

  f32x4 acc[4][4] = {};
  const int nt = p.K >> 5;

  // prologue: T0 -> slot0, T1 -> slot1; wait T0 landed (outstanding <= T1's 4)
  G_STAGE(0, 0);
  G_STAGE(1, 32);
  asm volatile("s_waitcnt vmcnt(4)" ::: "memory");
  __builtin_amdgcn_s_barrier();

#pragma unroll 1
  for (int t = 0; t < nt; t += 3) {
    G_SUBITER(0, t);
    G_SUBITER(1, t + 1);
    G_SUBITER(2, t + 2);
  }

#pragma unroll
  for (int i = 0; i < 4; ++i) {
#pragma unroll
    for (int j = 0; j < 4; ++j) {
#pragma unroll
      for (int r = 0; r < 4; ++r) {
        const long row = m0 + wr * 64 + i * 16 + lk * 4 + r;
        const long col = n0 + wc * 64 + j * 16 + l15;
        float v = acc[i][j][r];
        if constexpr (EP == EP_B16) {
          v += p.bias[col];
          p.outb[row * p.ldb + col] = (bf16)v;
        } else if constexpr (EP == EP_KV2) {
          v += p.bias[col];
          if (col < 1024) p.outb[row * p.ldb + col] = (bf16)v;          // K
          else p.outb2[row * p.ldb2 + (col - 1024)] = (bf16)v;          // V
        } else if constexpr (EP == EP_GELU) {
          v += p.bias[col];
          float g = 0.5f * v * (1.0f + erff(v * 0.70710678118654752f));
          p.outb[row * p.ldb + col] = (bf16)g;
        } else if constexpr (EP == EP_SIGRX) {
          if (col >= 1024) {
            float sg = 1.0f / (1.0f + __expf(-(v - p.bg[col - 1024])));
            p.outb2[row * p.ldb2 + (col - 1024)] = (bf16)sg;            // z
          } else {
            float sg = 1.0f / (1.0f + __expf(-v));
            p.outb[row * p.ldb + col] = (bf16)(sg * p.xbuf[row * 1024 + col]);  // r*x
          }
        } else if constexpr (EP == EP_GRU) {
          float z = (float)p.zbuf[row * 1024 + col];
          float x = p.xbuf[row * 1024 + col];
          float vc = fminf(fmaxf(v, -15.f), 15.f);
          float e2 = __expf(2.0f * vc);
          float th = (e2 - 1.0f) / (e2 + 1.0f);
          float o = (1.0f - z) * x + z * th;
          p.outf[row * p.ldf + col] = o;
          if (p.outb != nullptr) p.outb[row * p.ldb + col] = (bf16)o;
        }
      }
    }
  }
}

// ---------------------------------------------------------------------------
extern "C" void kernel_launch(void* const* d_in, const int* in_sizes, int n_in,
                              void* d_out, int out_size, void* d_ws, size_t ws_size,
                              hipStream_t stream) {
  const float* inputs = (const float*)d_in[0];
  const float* posemb = (const float*)d_in[1];
  const float* u_in = (const float*)d_in[2];
  const float* v_in = (const float*)d_in[3];
  const float* memory = (const float*)d_in[4];
  // d_in[5] = mask: analytic (unmasked iff j <= i+256), not read.
  const float* ln1_g = (const float*)d_in[6];
  const float* ln1_b = (const float*)d_in[7];
  const float* ln2_g = (const float*)d_in[8];
  const float* ln2_b = (const float*)d_in[9];
  const float* W_kv = (const float*)d_in[10];
  const float* b_kv = (const float*)d_in[11];
  const float* W_q = (const float*)d_in[12];
  const float* b_q = (const float*)d_in[13];
  const float* W_pos = (const float*)d_in[14];
  const float* b_pos = (const float*)d_in[15];
  const float* W_o = (const float*)d_in[16];
  const float* b_o = (const float*)d_in[17];
  const float* g1_Wr = (const float*)d_in[18];
  const float* g1_Ur = (const float*)d_in[19];
  const float* g1_Wz = (const float*)d_in[20];
  const float* g1_Uz = (const float*)d_in[21];
  const float* g1_Wg = (const float*)d_in[22];
  const float* g1_Ug = (const float*)d_in[23];
  const float* g1_bg = (const float*)d_in[24];
  const float* g2_Wr = (const float*)d_in[25];
  const float* g2_Ur = (const float*)d_in[26];
  const float* g2_Wz = (const float*)d_in[27];
  const float* g2_Uz = (const float*)d_in[28];
  const float* g2_Wg = (const float*)d_in[29];
  const float* g2_Ug = (const float*)d_in[30];
  const float* g2_bg = (const float*)d_in[31];
  const float* W_m1 = (const float*)d_in[32];
  const float* b_m1 = (const float*)d_in[33];
  const float* W_m2 = (const float*)d_in[34];
  const float* b_m2 = (const float*)d_in[35];
  float* out = (float*)d_out;
  float* o1 = out;  // f32 o1 parked in d_out (fully rewritten s11, read 12/15/16)

  const size_t MB = 1024UL * 1024UL;
  const size_t sizeB = 154 * MB;
  const size_t sizeA = 196 * MB;
  const bool A = (ws_size >= sizeA);
  if (!A && ws_size < sizeB) {  // canary: absmax ~3.4e38 => ws too small
    hipMemsetAsync(d_out, 0x7F, 256, stream);
    return;
  }

  char* w = (char*)d_ws;
  size_t off = 0;
  auto take = [&](size_t bytes) { char* p = w + off; off += bytes; return p; };
  char* RW = take(A ? 50 * MB : 8 * MB);
  bf16* posbf = (bf16*)take(1 * MB);
  bf16* rbf = (bf16*)take(1 * MB);
  char* R3 = take(32 * MB);   // x1(1-4) | valT(7-8) | y1@0(9-11), x2@16M(12-13) | m2@0(14-16)
  char* R45 = take(64 * MB);  // Kbuf@0 + Vbuf@32M (4-8) | mh 64MB (13-14)
  char* R6 = take(16 * MB);   // xb16(1-10) | o1b(11-16)
  char* R7 = take(16 * MB);   // qb(5-8) | rx(10-16)
  char* R8 = take(16 * MB);   // a1b(8-9) | z1b(10-16)

  bf16* WT = (bf16*)RW;
  bf16* WkvT  = A ? (bf16*)(RW + 0 * MB)  : WT;
  bf16* WqT   = A ? (bf16*)(RW + 4 * MB)  : WT;
  bf16* WposT = A ? (bf16*)(RW + 6 * MB)  : WT;
  bf16* WoT   = A ? (bf16*)(RW + 8 * MB)  : WT;
  bf16* G1rz  = A ? (bf16*)(RW + 10 * MB) : WT;
  bf16* G1g   = A ? (bf16*)(RW + 18 * MB) : WT;
  bf16* Wm1T  = A ? (bf16*)(RW + 22 * MB) : WT;
  bf16* Wm2T  = A ? (bf16*)(RW + 30 * MB) : WT;
  bf16* G2rz  = A ? (bf16*)(RW + 38 * MB) : WT;
  bf16* G2g   = A ? (bf16*)(RW + 46 * MB) : WT;

  bf16* x1 = (bf16*)R3;
  bf16* valT = (bf16*)R3;
  bf16* y1 = (bf16*)R3;
  bf16* x2 = (bf16*)(R3 + 16 * MB);
  bf16* m2 = (bf16*)R3;
  bf16* Kbuf = (bf16*)R45;
  bf16* Vbuf = (bf16*)(R45 + 32 * MB);
  bf16* mh = (bf16*)R45;
  bf16* xb16 = (bf16*)R6;
  bf16* o1b = (bf16*)R6;
  bf16* qb = (bf16*)R7;
  bf16* rx = (bf16*)R7;
  bf16* a1b = (bf16*)R8;
  bf16* z1b = (bf16*)R8;

  dim3 blk(256);
  auto addT = [](TPack& p, const float* src, bf16* dst, int K, int N, int ldd) {
    TDesc& d = p.d[p.nd++];
    d.src = src; d.dst = dst; d.N = N; d.ldd = ldd; d.start = p.total;
    p.total += (N / 64) * (K / 64);
  };
  auto runT = [&](TPack& p) {
    wtrans_multi<<<dim3(p.total), blk, 0, stream>>>(p);
  };
  auto T_kv = [&](TPack& p) { addT(p, W_kv, WkvT, 1024, 2048, 1024); };
  auto T_q = [&](TPack& p) { addT(p, W_q, WqT, 1024, 1024, 1024); };
  auto T_pos = [&](TPack& p) { addT(p, W_pos, WposT, 1024, 1024, 1024); };
  auto T_o = [&](TPack& p) { addT(p, W_o, WoT, 1024, 1024, 1024); };
  auto T_g1rz = [&](TPack& p) {
    addT(p, g1_Wr, G1rz, 1024, 1024, 2048);
    addT(p, g1_Ur, G1rz + 1024, 1024, 1024, 2048);
    addT(p, g1_Wz, G1rz + 1024L * 2048, 1024, 1024, 2048);
    addT(p, g1_Uz, G1rz + 1024L * 2048 + 1024, 1024, 1024, 2048);
  };
  auto T_g1g = [&](TPack& p) {
    addT(p, g1_Wg, G1g, 1024, 1024, 2048);
    addT(p, g1_Ug, G1g + 1024, 1024, 1024, 2048);
  };
  auto T_m1 = [&](TPack& p) { addT(p, W_m1, Wm1T, 1024, 4096, 1024); };
  auto T_m2 = [&](TPack& p) { addT(p, W_m2, Wm2T, 4096, 1024, 4096); };
  auto T_g2rz = [&](TPack& p) {
    addT(p, g2_Wr, G2rz, 1024, 1024, 2048);
    addT(p, g2_Ur, G2rz + 1024, 1024, 1024, 2048);
    addT(p, g2_Wz, G2rz + 1024L * 2048, 1024, 1024, 2048);
    addT(p, g2_Uz, G2rz + 1024L * 2048 + 1024, 1024, 1024, 2048);
  };
  auto T_g2g = [&](TPack& p) {
    addT(p, g2_Wg, G2g, 1024, 1024, 2048);
    addT(p, g2_Ug, G2g + 1024, 1024, 1024, 2048);
  };
  auto maybeT = [&](auto builder) {
    if (!A) { TPack p{}; builder(p); runT(p); }
  };

  if (A) {  // one batched transpose for all 18 weights
    TPack p{};
    T_kv(p); T_q(p); T_pos(p); T_o(p); T_g1rz(p); T_g1g(p);
    T_m1(p); T_m2(p); T_g2rz(p); T_g2g(p);
    runT(p);
  }

  // 1. LN1 over [memory; inputs] -> x1; raw inputs bf16 -> xb16
  ln_kernel<<<16384, blk, 0, stream>>>(memory, inputs, ln1_g, ln1_b, x1, 1024,
                                       xb16, 1024, 8192);
  // 2. pos_embedding -> bf16
  cvt_bf16_kernel<<<512, blk, 0, stream>>>(posemb, posbf);

  // 4. kv GEMM: K -> Kbuf, V -> Vbuf (both coalesced)
  maybeT(T_kv);
  {
    GP p{};
    p.A0 = p.A1 = x1; p.lda0 = p.lda1 = 1024; p.ksplit = 1 << 30; p.K = 1024;
    p.B = WkvT; p.bias = b_kv; p.outb = Kbuf; p.ldb = 1024;
    p.outb2 = Vbuf; p.ldb2 = 1024;
    gemm_bt<EP_KV2><<<dim3(16, 128), blk, 0, stream>>>(p);
  }
  // 5. q = inputs @ W_q + b_q -> qb (u/v added inside attention)
  maybeT(T_q);
  {
    GP p{};
    p.A0 = p.A1 = xb16; p.lda0 = p.lda1 = 1024; p.ksplit = 1 << 30; p.K = 1024;
    p.B = WqT; p.bias = b_q; p.outb = qb; p.ldb = 1024;
    gemm_bt<EP_B16><<<dim3(8, 64), blk, 0, stream>>>(p);
  }
  // 6. r = pos_embedding @ W_pos + b_pos -> rbf
  maybeT(T_pos);
  {
    GP p{};
    p.A0 = p.A1 = posbf; p.lda0 = p.lda1 = 1024; p.ksplit = 1 << 30; p.K = 1024;
    p.B = WposT; p.bias = b_pos; p.outb = rbf; p.ldb = 1024;
    gemm_bt<EP_B16><<<dim3(8, 4), blk, 0, stream>>>(p);
  }
  // 7. V transpose (x1 dead; valT overlays R3)
  valt_kernel<<<dim3(32, 16, 8), blk, 0, stream>>>(Vbuf, valT);
  // 8. fused attention -> a1b
  attn_kernel<<<dim3(2048), blk, 0, stream>>>(qb, u_in, v_in, Kbuf, rbf, valT, a1b);
  // 9. y1 = gelu(a1 @ W_o + b_o)
  maybeT(T_o);
  {
    GP p{};
    p.A0 = p.A1 = a1b; p.lda0 = p.lda1 = 1024; p.ksplit = 1 << 30; p.K = 1024;
    p.B = WoT; p.bias = b_o; p.outb = y1; p.ldb = 1024;
    gemm_bt<EP_GELU><<<dim3(8, 64), blk, 0, stream>>>(p);
  }
  // 10. gate1 r/z: [y1|x] @ [Wr Ur; Wz Uz]; r*x -> rx, z -> z1b
  maybeT(T_g1rz);
  {
    GP p{};
    p.A0 = y1; p.lda0 = 1024; p.A1 = xb16; p.lda1 = 1024; p.ksplit = 1024; p.K = 2048;
    p.B = G1rz; p.bg = g1_bg; p.xbuf = inputs;
    p.outb = rx; p.ldb = 1024; p.outb2 = z1b; p.ldb2 = 1024;
    gemm_bt<EP_SIGRX><<<dim3(16, 64), blk, 0, stream>>>(p);
  }
  // 11. gate1 h + combine: o1 = (1-z)*x + z*tanh([y1|rx] @ [Wg;Ug])
  maybeT(T_g1g);
  {
    GP p{};
    p.A0 = y1; p.lda0 = 1024; p.A1 = rx; p.lda1 = 1024; p.ksplit = 1024; p.K = 2048;
    p.B = G1g; p.zbuf = z1b; p.xbuf = inputs;
    p.outf = o1; p.ldf = 1024; p.outb = o1b; p.ldb = 1024;
    gemm_bt<EP_GRU><<<dim3(8, 64), blk, 0, stream>>>(p);
  }
  // 12. LN2(o1) -> x2
  ln_kernel<<<8192, blk, 0, stream>>>(o1, nullptr, ln2_g, ln2_b, x2, 1024,
                                      nullptr, 0, 1 << 30);
  // 13. mh = gelu(x2 @ W_m1 + b_m1)
  maybeT(T_m1);
  {
    GP p{};
    p.A0 = p.A1 = x2; p.lda0 = p.lda1 = 1024; p.ksplit = 1 << 30; p.K = 1024;
    p.B = Wm1T; p.bias = b_m1; p.outb = mh; p.ldb = 4096;
    gemm_bt<EP_GELU><<<dim3(32, 64), blk, 0, stream>>>(p);
  }
  // 14. m2 = gelu(mh @ W_m2 + b_m2)
  maybeT(T_m2);
  {
    GP p{};
    p.A0 = p.A1 = mh; p.lda0 = p.lda1 = 4096; p.ksplit = 1 << 30; p.K = 4096;
    p.B = Wm2T; p.bias = b_m2; p.outb = m2; p.ldb = 1024;
    gemm_bt<EP_GELU><<<dim3(8, 64), blk, 0, stream>>>(p);
  }
  // 15. gate2 r/z: [m2|o1b]; r*o1 -> rx, z -> z1b
  maybeT(T_g2rz);
  {
    GP p{};
    p.A0 = m2; p.lda0 = 1024; p.A1 = o1b; p.lda1 = 1024; p.ksplit = 1024; p.K = 2048;
    p.B = G2rz; p.bg = g2_bg; p.xbuf = o1;
    p.outb = rx; p.ldb = 1024; p.outb2 = z1b; p.ldb2 = 1024;
    gemm_bt<EP_SIGRX><<<dim3(16, 64), blk, 0, stream>>>(p);
  }
  // 16. gate2 h + combine -> d_out (in-place over o1: own-element read/write)
  maybeT(T_g2g);
  {
    GP p{};
    p.A0 = m2; p.lda0 = 1024; p.A1 = rx; p.lda1 = 1024; p.ksplit = 1024; p.K = 2048;
    p.B = G2g; p.zbuf = z1b; p.xbuf = o1;
    p.outf = out; p.ldf = 1024; p.outb = nullptr;
    gemm_bt<EP_GRU><<<dim3(8, 64), blk, 0, stream>>>(p);
  }
}

// Round 10
// 840.305 us; speedup vs baseline: 1.0522x; 1.0107x over previous
//
#include <hip/hip_runtime.h>
#include <cstdint>

// ---------------------------------------------------------------------------
// GatedTransformerXLLayer on MI355X (gfx950).
// D=1024, H=16, HD=64, FF=4096, CUR=256, MEM=256, BS=32, FULL=512.
// bf16 MFMA (16x16x32); GEMM: 3-slot ring LDS + counted vmcnt + raw
// s_barrier (T4) + XCD swizzle + setprio (T5) + T2 XOR swizzle; templated
// tile: BIG=256x128 (per-wave 128x64 acc[8][4], 576 B LDS/MFMA, 32
// MFMA/barrier) for the large GEMMs, 128x128 for the rest.
// Fused attention with staged K/R/V, pre-scaled q, chunk skipping,
// single-pass __expf softmax with deferred 1/sum.
// ---------------------------------------------------------------------------

typedef __bf16 bf16;
typedef bf16 bf16x4 __attribute__((ext_vector_type(4)));
typedef bf16 bf16x8 __attribute__((ext_vector_type(8)));
typedef float f32x4 __attribute__((ext_vector_type(4)));

#define MFMA16(a, b, c) __builtin_amdgcn_mfma_f32_16x16x32_bf16((a), (b), (c), 0, 0, 0)

__device__ __forceinline__ void gl2lds16(const void* g, void* l) {
  __builtin_amdgcn_global_load_lds(
      (const __attribute__((address_space(1))) unsigned int*)g,
      (__attribute__((address_space(3))) unsigned int*)l, 16, 0, 0);
}

__device__ __forceinline__ bf16x8 ldg8(const bf16* p) { return *(const bf16x8*)p; }

// XOR-swizzled index into a [16][512] bf16 wave-slice (u16 units).
__device__ __forceinline__ int sidx(int row, int col) {
  return (row * 512 + col) ^ ((row & 7) << 3);
}

// ---------------- LayerNorm (one row per block, 256 thr x float4) ----------
__global__ __launch_bounds__(256) void ln_kernel(
    const float* __restrict__ src0, const float* __restrict__ src1,
    const float* __restrict__ gam, const float* __restrict__ bet,
    bf16* __restrict__ out, long ldo,
    bf16* __restrict__ raw, long ldraw, int rawstart) {
  const int row = blockIdx.x;
  const int tid = threadIdx.x;
  const float* src = (src1 != nullptr && row >= rawstart)
                         ? (src1 + (long)(row - rawstart) * 1024)
                         : (src0 + (long)row * 1024);
  float4 v = ((const float4*)src)[tid];
  float s = v.x + v.y + v.z + v.w;
#pragma unroll
  for (int o = 32; o > 0; o >>= 1) s += __shfl_down(s, o);
  __shared__ float red[8];
  const int wv = tid >> 6, lane = tid & 63;
  if (lane == 0) red[wv] = s;
  __syncthreads();
  float mean = (red[0] + red[1] + red[2] + red[3]) * (1.0f / 1024.0f);
  float dx = v.x - mean, dy = v.y - mean, dz = v.z - mean, dw = v.w - mean;
  float ss = dx * dx + dy * dy + dz * dz + dw * dw;
#pragma unroll
  for (int o = 32; o > 0; o >>= 1) ss += __shfl_down(ss, o);
  if (lane == 0) red[4 + wv] = ss;
  __syncthreads();
  float var = (red[4] + red[5] + red[6] + red[7]) * (1.0f / 1024.0f);
  float rstd = rsqrtf(var + 1e-5f);
  int c = tid * 4;
  float4 g4 = ((const float4*)gam)[tid];
  float4 b4 = ((const float4*)bet)[tid];
  bf16x4 o4;
  o4[0] = (bf16)(dx * rstd * g4.x + b4.x);
  o4[1] = (bf16)(dy * rstd * g4.y + b4.y);
  o4[2] = (bf16)(dz * rstd * g4.z + b4.z);
  o4[3] = (bf16)(dw * rstd * g4.w + b4.w);
  *(bf16x4*)(out + (long)row * ldo + c) = o4;
  if (raw != nullptr && row >= rawstart) {
    bf16x4 r4;
    r4[0] = (bf16)v.x; r4[1] = (bf16)v.y; r4[2] = (bf16)v.z; r4[3] = (bf16)v.w;
    *(bf16x4*)(raw + (long)(row - rawstart) * ldraw + c) = r4;
  }
}

// ---------------- fp32 -> bf16 convert -------------------------------------
__global__ __launch_bounds__(256) void cvt_bf16_kernel(const float* __restrict__ s,
                                                       bf16* __restrict__ d) {
  long i = ((long)blockIdx.x * 256 + threadIdx.x) * 4;
  float4 v = *(const float4*)(s + i);
  bf16x4 o;
  o[0] = (bf16)v.x; o[1] = (bf16)v.y; o[2] = (bf16)v.z; o[3] = (bf16)v.w;
  *(bf16x4*)(d + i) = o;
}

// ---------------- batched weight transpose+convert -------------------------
struct TDesc { const float* src; bf16* dst; int N; int ldd; int start; };
struct TPack { TDesc d[18]; int nd; int total; };

__global__ __launch_bounds__(256) void wtrans_multi(TPack p) {
  __shared__ bf16 t[64][66];
  const int tile = blockIdx.x;
  int wi = 0;
#pragma unroll 1
  for (int i = 1; i < p.nd; ++i)
    if (tile >= p.d[i].start) wi = i;
  const float* src = p.d[wi].src;
  bf16* dst = p.d[wi].dst;
  const int N = p.d[wi].N;
  const long ldd = p.d[wi].ldd;
  const int local = tile - p.d[wi].start;
  const int tiles_x = N >> 6;
  const int n0 = (local % tiles_x) * 64, k0 = (local / tiles_x) * 64;
  const int tx = threadIdx.x & 63, ty = threadIdx.x >> 6;
#pragma unroll
  for (int i = 0; i < 64; i += 4)
    t[ty + i][tx] = (bf16)src[(long)(k0 + ty + i) * N + n0 + tx];
  __syncthreads();
#pragma unroll
  for (int i = 0; i < 64; i += 4)
    dst[(long)(n0 + ty + i) * ldd + k0 + tx] = t[tx][ty + i];
}

// ---------------- V transpose: Vbuf[t][1024] -> valT[(b*16+h)*64+d][j] -----
__global__ __launch_bounds__(256) void valt_kernel(const bf16* __restrict__ Vbuf,
                                                   bf16* __restrict__ valT) {
  __shared__ bf16 t[64][66];
  const int b = blockIdx.x, h = blockIdx.y, j0 = blockIdx.z * 64;
  const int jj = threadIdx.x >> 2, dg = (threadIdx.x & 3) * 16;
  const bf16* srcp = Vbuf + ((long)(j0 + jj) * 32 + b) * 1024 + h * 64 + dg;
  bf16x8 v0 = ldg8(srcp), v1 = ldg8(srcp + 8);
#pragma unroll
  for (int e = 0; e < 8; ++e) { t[jj][dg + e] = v0[e]; t[jj][dg + 8 + e] = v1[e]; }
  __syncthreads();
  const int dd = threadIdx.x >> 2, jg = (threadIdx.x & 3) * 16;
  bf16* dstp = valT + ((long)(b * 16 + h) * 64 + dd) * 512 + j0 + jg;
  bf16x8 o0, o1;
#pragma unroll
  for (int e = 0; e < 8; ++e) { o0[e] = t[jg + e][dd]; o1[e] = t[jg + 8 + e][dd]; }
  *(bf16x8*)dstp = o0;
  *(bf16x8*)(dstp + 8) = o1;
}

// ---------------- fused attention -----------------------------------------
__device__ __forceinline__ void stageKR(const char* rowbase, long strideB,
                                        bf16* stg, int tid) {
#pragma unroll
  for (int i = 0; i < 4; ++i) {
    const int slot = i * 256 + tid;
    const int row = slot >> 3;
    const int colb = ((slot << 4) & 127) ^ ((row & 7) << 4);
    gl2lds16(rowbase + (long)row * strideB + colb, (char*)stg + slot * 16);
  }
}
__device__ __forceinline__ void stageV(const char* rowbase, long strideB,
                                       bf16* stg, int tid) {
#pragma unroll
  for (int i = 0; i < 4; ++i) {
    const int slot = i * 256 + tid;
    const int row = slot >> 4;
    const int colb = ((slot << 4) & 255) ^ ((row & 7) << 4);
    gl2lds16(rowbase + (long)row * strideB + colb, (char*)stg + slot * 16);
  }
}
__device__ __forceinline__ bf16x8 rdKR(const bf16* stg, int rloc, int byteInRow) {
  const int addr = (rloc * 128 + byteInRow) ^ ((rloc & 7) << 4);
  return *(const bf16x8*)((const char*)stg + addr);
}
__device__ __forceinline__ bf16x8 rdV(const bf16* stg, int rloc, int byteInRow) {
  const int addr = (rloc * 256 + byteInRow) ^ ((rloc & 7) << 4);
  return *(const bf16x8*)((const char*)stg + addr);
}

__global__ __launch_bounds__(256, 2) void attn_kernel(
    const bf16* __restrict__ qb, const float* __restrict__ uvec,
    const float* __restrict__ vvec, const bf16* __restrict__ Kb,
    const bf16* __restrict__ rbf, const bf16* __restrict__ valT,
    bf16* __restrict__ a1out) {
  __shared__ __align__(16) bf16 s2[4][8192];   // 64KB wave-private S2/logit/P
  __shared__ __align__(16) bf16 stg[8192];     // 16KB shared staging
  const int tid = threadIdx.x;
  const int wv = tid >> 6, lane = tid & 63;
  const int l15 = lane & 15, lk = lane >> 4;
  const int bid = blockIdx.x;
  const int swzb = ((bid & 7) << 8) + (bid >> 3);  // nwg=2048, 256-chunks/XCD
  const int st = swzb & 3, h = (swzb >> 2) & 15, b = swzb >> 6;
  const int i0 = st * 64 + wv * 16;
  const long bh = (long)b * 16 + h;
  bf16* sw = s2[wv];
  const bool skipE = (st < 2);  // block-uniform masked-chunk skip

  const bf16* qp = qb + ((long)(i0 + l15) * 32 + b) * 1024 + h * 64 + lk * 8;
  bf16x8 q0 = ldg8(qp), q1 = ldg8(qp + 32);
  const float* up = uvec + h * 64 + lk * 8;
  const float* vp = vvec + h * 64 + lk * 8;
  bf16x8 a0u, a1u, a0v, a1v;
#pragma unroll
  for (int e = 0; e < 8; ++e) {
    float f0 = (float)q0[e], f1 = (float)q1[e];
    a0u[e] = (bf16)((f0 + up[e]) * 0.125f);
    a1u[e] = (bf16)((f1 + up[32 + e]) * 0.125f);
    a0v[e] = (bf16)((f0 + vp[e]) * 0.125f);
    a1v[e] = (bf16)((f1 + vp[32 + e]) * 0.125f);
  }

  // ---- Phase 1: S2 = (q+v)/8 R^T -> wave-private LDS, cols = raw index
#pragma unroll
  for (int c = 0; c < 4; ++c) {
    if (skipE && c == 0) continue;
    __syncthreads();
    stageKR((const char*)(rbf + (long)(c * 128) * 1024 + h * 64), 2048, stg, tid);
    __syncthreads();
#pragma unroll
    for (int jt = 0; jt < 8; ++jt) {
      bf16x8 b0 = rdKR(stg, jt * 16 + l15, lk * 16);
      bf16x8 b1 = rdKR(stg, jt * 16 + l15, 64 + lk * 16);
      f32x4 cc = {0.f, 0.f, 0.f, 0.f};
      cc = MFMA16(a0v, b0, cc);
      cc = MFMA16(a1v, b1, cc);
      const int jcol = (c * 8 + jt) * 16 + l15;
#pragma unroll
      for (int r = 0; r < 4; ++r) sw[sidx(lk * 4 + r, jcol)] = (bf16)cc[r];
    }
  }
  // ---- Phase 2: logits in-place (gather cols >= write col; wave-private)
#pragma unroll
  for (int c = 0; c < 4; ++c) {
    if (skipE && c == 3) continue;
    __syncthreads();
    stageKR((const char*)(Kb + ((long)(c * 128) * 32 + b) * 1024 + h * 64),
            65536, stg, tid);
    __syncthreads();
#pragma unroll
    for (int jt = 0; jt < 8; ++jt) {
      bf16x8 b0 = rdKR(stg, jt * 16 + l15, lk * 16);
      bf16x8 b1 = rdKR(stg, jt * 16 + l15, 64 + lk * 16);
      f32x4 cc = {0.f, 0.f, 0.f, 0.f};
      cc = MFMA16(a0u, b0, cc);
      cc = MFMA16(a1u, b1, cc);
      const int j = (c * 8 + jt) * 16 + l15;
      float lgv[4];
#pragma unroll
      for (int r = 0; r < 4; ++r) {
        const int i = i0 + lk * 4 + r;
        lgv[r] = (j <= i + 256)
                     ? (cc[r] + (float)sw[sidx(lk * 4 + r, j - i + 255)])
                     : -1e30f;
      }
#pragma unroll
      for (int r = 0; r < 4; ++r) sw[sidx(lk * 4 + r, j)] = (bf16)lgv[r];
    }
  }
  // ---- single-pass softmax, unnormalized; 1/sum deferred to PV epilogue
  float inv;
  {
    const int rr = lane & 15, pp = lane >> 4;
    const bool dead = skipE && (pp == 3);
    bf16x8 pk[16];
    float m = -3e38f;
    if (!dead) {
#pragma unroll
      for (int k = 0; k < 16; ++k)
        pk[k] = *(const bf16x8*)(sw + sidx(rr, pp * 128 + k * 8));
#pragma unroll
      for (int k = 0; k < 16; ++k)
#pragma unroll
        for (int e = 0; e < 8; ++e) m = fmaxf(m, (float)pk[k][e]);
    }
    m = fmaxf(m, __shfl_xor(m, 16));
    m = fmaxf(m, __shfl_xor(m, 32));
    float s = 0.f;
    if (!dead) {
#pragma unroll
      for (int k = 0; k < 16; ++k) {
        bf16x8 t;
#pragma unroll
        for (int e = 0; e < 8; ++e) {
          float ev = __expf((float)pk[k][e] - m);
          s += ev;
          t[e] = (bf16)ev;
        }
        *(bf16x8*)(sw + sidx(rr, pp * 128 + k * 8)) = t;
      }
    }
    s += __shfl_xor(s, 16);
    s += __shfl_xor(s, 32);
    inv = 1.0f / s;
  }
  // ---- Phase 3: O = (P V) * inv
  f32x4 oacc[4] = {};
  const char* vbase = (const char*)(valT + bh * 64 * 512);
#pragma unroll
  for (int c = 0; c < 4; ++c) {
    if (skipE && c == 3) continue;
    __syncthreads();
    stageV(vbase + c * 256, 1024, stg, tid);
    __syncthreads();
#pragma unroll
    for (int ksl = 0; ksl < 4; ++ksl) {
      const int ks = c * 4 + ksl;
      bf16x8 pa = *(const bf16x8*)(sw + sidx(l15, ks * 32 + lk * 8));
#pragma unroll
      for (int nt = 0; nt < 4; ++nt) {
        bf16x8 vb = rdV(stg, nt * 16 + l15, ksl * 64 + lk * 16);
        oacc[nt] = MFMA16(pa, vb, oacc[nt]);
      }
    }
  }
  float invr[4];
#pragma unroll
  for (int r = 0; r < 4; ++r) invr[r] = __shfl(inv, lk * 4 + r);
#pragma unroll
  for (int nt = 0; nt < 4; ++nt)
#pragma unroll
    for (int r = 0; r < 4; ++r) {
      const long t = (long)(i0 + lk * 4 + r) * 32 + b;
      a1out[t * 1024 + h * 64 + nt * 16 + l15] = (bf16)(oacc[nt][r] * invr[r]);
    }
}

// ---------------- templated ring GEMM with fused epilogues -----------------
// BIG=1: 256x128 tile, per-wave 128x64 (acc[8][4]); BIG=0: 128x128, 64x64.
// 3-slot ring, counted vmcnt(ALOADS+2), raw s_barrier, T2 swizzle, setprio.
enum { EP_B16 = 0, EP_KV2 = 1, EP_GELU = 2, EP_SIGRX = 3, EP_GRU = 4 };

struct GP {
  const bf16* A0; const bf16* A1;   // A split at k=ksplit (concat-K GEMMs)
  long lda0, lda1; int ksplit; int K;
  const bf16* B;                    // [N][K] bf16 (W^T), row stride K
  const float* bias;
  const float* bg;                  // EP_SIGRX
  const float* xbuf;                // EP_SIGRX (r*x), EP_GRU (combine x), f32
  const bf16* zbuf;                 // EP_GRU (z, bf16)
  float* outf; long ldf;
  bf16* outb; long ldb;
  bf16* outb2; long ldb2;
};

#define G_STAGE(BB, K0)                                                       \
  {                                                                           \
    const int k0_ = (K0);                                                     \
    _Pragma("unroll") for (int ii = 0; ii < ALOADS; ++ii) {                   \
      const int r_ = ii * 64 + (tid >> 2);                                    \
      const bf16* ag_ = (k0_ < p.ksplit)                                      \
          ? p.A0 + (m0 + r_) * p.lda0 + k0_ + skkx                            \
          : p.A1 + (m0 + r_) * p.lda1 + (k0_ - p.ksplit) + skkx;              \
      gl2lds16(ag_, As[BB] + (long)r_ * 32 + skk);                            \
    }                                                                         \
    gl2lds16(Bg0 + k0_, Bs[BB] + sdstB);                                      \
    gl2lds16(Bg1 + k0_, Bs[BB] + 64 * 32 + sdstB);                            \
  }

#define G_SUBITER(BB, TCUR)                                                   \
  if ((TCUR) < nt) {                                                          \
    bf16x8 af[MI], bfr[4];                                                    \
    _Pragma("unroll") for (int i = 0; i < MI; ++i)                            \
      af[i] = *(const bf16x8*)(As[BB] + (wr * (BM / 2) + i * 16 + l15) * 32 + lkx8); \
    _Pragma("unroll") for (int j = 0; j < 4; ++j)                             \
      bfr[j] = *(const bf16x8*)(Bs[BB] + (wc * 64 + j * 16 + l15) * 32 + lkx8); \
    if ((TCUR) + 2 < nt) G_STAGE((((BB) + 2) % 3), ((TCUR) + 2) * 32);        \
    __builtin_amdgcn_s_setprio(1);                                            \
    _Pragma("unroll") for (int i = 0; i < MI; ++i)                            \
      _Pragma("unroll") for (int j = 0; j < 4; ++j)                           \
          acc[i][j] = MFMA16(af[i], bfr[j], acc[i][j]);                       \
    __builtin_amdgcn_s_setprio(0);                                            \
    if ((TCUR) + 1 < nt) {                                                    \
      if ((TCUR) + 2 < nt)                                                    \
        asm volatile("s_waitcnt vmcnt(%0)" ::"i"(ALOADS + 2) : "memory");     \
      else                                                                    \
        asm volatile("s_waitcnt vmcnt(0)" ::: "memory");                      \
      __builtin_amdgcn_s_barrier();                                           \
    }                                                                         \
  }

template <int EP, int BIG>
__global__ __launch_bounds__(256, BIG ? 2 : 3) void gemm_bt(GP p) {
  constexpr int BM = BIG ? 256 : 128;
  constexpr int MI = BIG ? 8 : 4;
  constexpr int ALOADS = BIG ? 4 : 2;
  __shared__ __align__(16) bf16 As[3][BM * 32];
  __shared__ __align__(16) bf16 Bs[3][128 * 32];
  const int tid = threadIdx.x;
  const int lane = tid & 63;
  const int wv = tid >> 6;
  const int wr = wv >> 1, wc = wv & 1;
  const int l15 = lane & 15, lk = lane >> 4;
  const int lkx8 = (lk ^ ((l15 >> 1) & 3)) * 8;   // T2 swizzled read chunk
  const int nx = gridDim.x;
  const int nwg = nx * gridDim.y;
  const int bid = blockIdx.y * nx + blockIdx.x;
  const int qq = nwg >> 3, rr = nwg & 7, xc = bid & 7, loc = bid >> 3;
  const int swz = (xc < rr ? xc * (qq + 1) : rr * (qq + 1) + (xc - rr) * qq) + loc;
  const long n0 = (long)(swz % nx) * 128;
  const long m0 = (long)(swz / nx) * BM;
  const int skk = (tid & 3) * 8;                        // linear gl2lds dest
  const int skkx = ((tid & 3) ^ ((tid >> 3) & 3)) * 8;  // inverse-swz source
  const long sdstB = (long)(tid >> 2) * 32 + skk;

  const bf16* Bg0 = p.B + (n0 + (tid >> 2)) * (long)p.K + skkx;
  const bf16* Bg1 = p.B + (n0 + (tid >> 2) + 64) * (long)p.K + skkx;

  f32x4 acc[MI][4] = {};
  const int nt = p.K >> 5;

  // prologue: T0 -> slot0, T1 -> slot1; wait T0 landed
  G_STAGE(0, 0);
  G_STAGE(1, 32);
  asm volatile("s_waitcnt vmcnt(%0)" ::"i"(ALOADS + 2) : "memory");
  __builtin_amdgcn_s_barrier();

#pragma unroll 1
  for (int t = 0; t < nt; t += 3) {
    G_SUBITER(0, t);
    G_SUBITER(1, t + 1);
    G_SUBITER(2, t + 2);
  }

#pragma unroll
  for (int i = 0; i < MI; ++i) {
#pragma unroll
    for (int j = 0; j < 4; ++j) {
#pragma unroll
      for (int r = 0; r < 4; ++r) {
        const long row = m0 + wr * (BM / 2) + i * 16 + lk * 4 + r;
        const long col = n0 + wc * 64 + j * 16 + l15;
        float v = acc[i][j][r];
        if constexpr (EP == EP_B16) {
          v += p.bias[col];
          p.outb[row * p.ldb + col] = (bf16)v;
        } else if constexpr (EP == EP_KV2) {
          v += p.bias[col];
          if (col < 1024) p.outb[row * p.ldb + col] = (bf16)v;          // K
          else p.outb2[row * p.ldb2 + (col - 1024)] = (bf16)v;          // V
        } else if constexpr (EP == EP_GELU) {
          v += p.bias[col];
          float g = 0.5f * v * (1.0f + erff(v * 0.70710678118654752f));
          p.outb[row * p.ldb + col] = (bf16)g;
        } else if constexpr (EP == EP_SIGRX) {
          if (col >= 1024) {
            float sg = 1.0f / (1.0f + __expf(-(v - p.bg[col - 1024])));
            p.outb2[row * p.ldb2 + (col - 1024)] = (bf16)sg;            // z
          } else {
            float sg = 1.0f / (1.0f + __expf(-v));
            p.outb[row * p.ldb + col] = (bf16)(sg * p.xbuf[row * 1024 + col]);  // r*x
          }
        } else if constexpr (EP == EP_GRU) {
          float z = (float)p.zbuf[row * 1024 + col];
          float x = p.xbuf[row * 1024 + col];
          float vc = fminf(fmaxf(v, -15.f), 15.f);
          float e2 = __expf(2.0f * vc);
          float th = (e2 - 1.0f) / (e2 + 1.0f);
          float o = (1.0f - z) * x + z * th;
          p.outf[row * p.ldf + col] = o;
          if (p.outb != nullptr) p.outb[row * p.ldb + col] = (bf16)o;
        }
      }
    }
  }
}

// ---------------------------------------------------------------------------
extern "C" void kernel_launch(void* const* d_in, const int* in_sizes, int n_in,
                              void* d_out, int out_size, void* d_ws, size_t ws_size,
                              hipStream_t stream) {
  const float* inputs = (const float*)d_in[0];
  const float* posemb = (const float*)d_in[1];
  const float* u_in = (const float*)d_in[2];
  const float* v_in = (const float*)d_in[3];
  const float* memory = (const float*)d_in[4];
  // d_in[5] = mask: analytic (unmasked iff j <= i+256), not read.
  const float* ln1_g = (const float*)d_in[6];
  const float* ln1_b = (const float*)d_in[7];
  const float* ln2_g = (const float*)d_in[8];
  const float* ln2_b = (const float*)d_in[9];
  const float* W_kv = (const float*)d_in[10];
  const float* b_kv = (const float*)d_in[11];
  const float* W_q = (const float*)d_in[12];
  const float* b_q = (const float*)d_in[13];
  const float* W_pos = (const float*)d_in[14];
  const float* b_pos = (const float*)d_in[15];
  const float* W_o = (const float*)d_in[16];
  const float* b_o = (const float*)d_in[17];
  const float* g1_Wr = (const float*)d_in[18];
  const float* g1_Ur = (const float*)d_in[19];
  const float* g1_Wz = (const float*)d_in[20];
  const float* g1_Uz = (const float*)d_in[21];
  const float* g1_Wg = (const float*)d_in[22];
  const float* g1_Ug = (const float*)d_in[23];
  const float* g1_bg = (const float*)d_in[24];
  const float* g2_Wr = (const float*)d_in[25];
  const float* g2_Ur = (const float*)d_in[26];
  const float* g2_Wz = (const float*)d_in[27];
  const float* g2_Uz = (const float*)d_in[28];
  const float* g2_Wg = (const float*)d_in[29];
  const float* g2_Ug = (const float*)d_in[30];
  const float* g2_bg = (const float*)d_in[31];
  const float* W_m1 = (const float*)d_in[32];
  const float* b_m1 = (const float*)d_in[33];
  const float* W_m2 = (const float*)d_in[34];
  const float* b_m2 = (const float*)d_in[35];
  float* out = (float*)d_out;
  float* o1 = out;  // f32 o1 parked in d_out (fully rewritten s11, read 12/15/16)

  const size_t MB = 1024UL * 1024UL;
  const size_t sizeB = 154 * MB;
  const size_t sizeA = 196 * MB;
  const bool A = (ws_size >= sizeA);
  if (!A && ws_size < sizeB) {  // canary: absmax ~3.4e38 => ws too small
    hipMemsetAsync(d_out, 0x7F, 256, stream);
    return;
  }

  char* w = (char*)d_ws;
  size_t off = 0;
  auto take = [&](size_t bytes) { char* p = w + off; off += bytes; return p; };
  char* RW = take(A ? 50 * MB : 8 * MB);
  bf16* posbf = (bf16*)take(1 * MB);
  bf16* rbf = (bf16*)take(1 * MB);
  char* R3 = take(32 * MB);   // x1(1-4) | valT(7-8) | y1@0(9-11), x2@16M(12-13) | m2@0(14-16)
  char* R45 = take(64 * MB);  // Kbuf@0 + Vbuf@32M (4-8) | mh 64MB (13-14)
  char* R6 = take(16 * MB);   // xb16(1-10) | o1b(11-16)
  char* R7 = take(16 * MB);   // qb(5-8) | rx(10-16)
  char* R8 = take(16 * MB);   // a1b(8-9) | z1b(10-16)

  bf16* WT = (bf16*)RW;
  bf16* WkvT  = A ? (bf16*)(RW + 0 * MB)  : WT;
  bf16* WqT   = A ? (bf16*)(RW + 4 * MB)  : WT;
  bf16* WposT = A ? (bf16*)(RW + 6 * MB)  : WT;
  bf16* WoT   = A ? (bf16*)(RW + 8 * MB)  : WT;
  bf16* G1rz  = A ? (bf16*)(RW + 10 * MB) : WT;
  bf16* G1g   = A ? (bf16*)(RW + 18 * MB) : WT;
  bf16* Wm1T  = A ? (bf16*)(RW + 22 * MB) : WT;
  bf16* Wm2T  = A ? (bf16*)(RW + 30 * MB) : WT;
  bf16* G2rz  = A ? (bf16*)(RW + 38 * MB) : WT;
  bf16* G2g   = A ? (bf16*)(RW + 46 * MB) : WT;

  bf16* x1 = (bf16*)R3;
  bf16* valT = (bf16*)R3;
  bf16* y1 = (bf16*)R3;
  bf16* x2 = (bf16*)(R3 + 16 * MB);
  bf16* m2 = (bf16*)R3;
  bf16* Kbuf = (bf16*)R45;
  bf16* Vbuf = (bf16*)(R45 + 32 * MB);
  bf16* mh = (bf16*)R45;
  bf16* xb16 = (bf16*)R6;
  bf16* o1b = (bf16*)R6;
  bf16* qb = (bf16*)R7;
  bf16* rx = (bf16*)R7;
  bf16* a1b = (bf16*)R8;
  bf16* z1b = (bf16*)R8;

  dim3 blk(256);
  auto addT = [](TPack& p, const float* src, bf16* dst, int K, int N, int ldd) {
    TDesc& d = p.d[p.nd++];
    d.src = src; d.dst = dst; d.N = N; d.ldd = ldd; d.start = p.total;
    p.total += (N / 64) * (K / 64);
  };
  auto runT = [&](TPack& p) {
    wtrans_multi<<<dim3(p.total), blk, 0, stream>>>(p);
  };
  auto T_kv = [&](TPack& p) { addT(p, W_kv, WkvT, 1024, 2048, 1024); };
  auto T_q = [&](TPack& p) { addT(p, W_q, WqT, 1024, 1024, 1024); };
  auto T_pos = [&](TPack& p) { addT(p, W_pos, WposT, 1024, 1024, 1024); };
  auto T_o = [&](TPack& p) { addT(p, W_o, WoT, 1024, 1024, 1024); };
  auto T_g1rz = [&](TPack& p) {
    addT(p, g1_Wr, G1rz, 1024, 1024, 2048);
    addT(p, g1_Ur, G1rz + 1024, 1024, 1024, 2048);
    addT(p, g1_Wz, G1rz + 1024L * 2048, 1024, 1024, 2048);
    addT(p, g1_Uz, G1rz + 1024L * 2048 + 1024, 1024, 1024, 2048);
  };
  auto T_g1g = [&](TPack& p) {
    addT(p, g1_Wg, G1g, 1024, 1024, 2048);
    addT(p, g1_Ug, G1g + 1024, 1024, 1024, 2048);
  };
  auto T_m1 = [&](TPack& p) { addT(p, W_m1, Wm1T, 1024, 4096, 1024); };
  auto T_m2 = [&](TPack& p) { addT(p, W_m2, Wm2T, 4096, 1024, 4096); };
  auto T_g2rz = [&](TPack& p) {
    addT(p, g2_Wr, G2rz, 1024, 1024, 2048);
    addT(p, g2_Ur, G2rz + 1024, 1024, 1024, 2048);
    addT(p, g2_Wz, G2rz + 1024L * 2048, 1024, 1024, 2048);
    addT(p, g2_Uz, G2rz + 1024L * 2048 + 1024, 1024, 1024, 2048);
  };
  auto T_g2g = [&](TPack& p) {
    addT(p, g2_Wg, G2g, 1024, 1024, 2048);
    addT(p, g2_Ug, G2g + 1024, 1024, 1024, 2048);
  };
  auto maybeT = [&](auto builder) {
    if (!A) { TPack p{}; builder(p); runT(p); }
  };

  if (A) {  // one batched transpose for all 18 weights
    TPack p{};
    T_kv(p); T_q(p); T_pos(p); T_o(p); T_g1rz(p); T_g1g(p);
    T_m1(p); T_m2(p); T_g2rz(p); T_g2g(p);
    runT(p);
  }

  // 1. LN1 over [memory; inputs] -> x1; raw inputs bf16 -> xb16
  ln_kernel<<<16384, blk, 0, stream>>>(memory, inputs, ln1_g, ln1_b, x1, 1024,
                                       xb16, 1024, 8192);
  // 2. pos_embedding -> bf16
  cvt_bf16_kernel<<<512, blk, 0, stream>>>(posemb, posbf);

  // 4. kv GEMM (BIG): K -> Kbuf, V -> Vbuf
  maybeT(T_kv);
  {
    GP p{};
    p.A0 = p.A1 = x1; p.lda0 = p.lda1 = 1024; p.ksplit = 1 << 30; p.K = 1024;
    p.B = WkvT; p.bias = b_kv; p.outb = Kbuf; p.ldb = 1024;
    p.outb2 = Vbuf; p.ldb2 = 1024;
    gemm_bt<EP_KV2, 1><<<dim3(16, 64), blk, 0, stream>>>(p);
  }
  // 5. q = inputs @ W_q + b_q -> qb
  maybeT(T_q);
  {
    GP p{};
    p.A0 = p.A1 = xb16; p.lda0 = p.lda1 = 1024; p.ksplit = 1 << 30; p.K = 1024;
    p.B = WqT; p.bias = b_q; p.outb = qb; p.ldb = 1024;
    gemm_bt<EP_B16, 0><<<dim3(8, 64), blk, 0, stream>>>(p);
  }
  // 6. r = pos_embedding @ W_pos + b_pos -> rbf
  maybeT(T_pos);
  {
    GP p{};
    p.A0 = p.A1 = posbf; p.lda0 = p.lda1 = 1024; p.ksplit = 1 << 30; p.K = 1024;
    p.B = WposT; p.bias = b_pos; p.outb = rbf; p.ldb = 1024;
    gemm_bt<EP_B16, 0><<<dim3(8, 4), blk, 0, stream>>>(p);
  }
  // 7. V transpose (x1 dead; valT overlays R3)
  valt_kernel<<<dim3(32, 16, 8), blk, 0, stream>>>(Vbuf, valT);
  // 8. fused attention -> a1b
  attn_kernel<<<dim3(2048), blk, 0, stream>>>(qb, u_in, v_in, Kbuf, rbf, valT, a1b);
  // 9. y1 = gelu(a1 @ W_o + b_o)
  maybeT(T_o);
  {
    GP p{};
    p.A0 = p.A1 = a1b; p.lda0 = p.lda1 = 1024; p.ksplit = 1 << 30; p.K = 1024;
    p.B = WoT; p.bias = b_o; p.outb = y1; p.ldb = 1024;
    gemm_bt<EP_GELU, 0><<<dim3(8, 64), blk, 0, stream>>>(p);
  }
  // 10. gate1 r/z (BIG): [y1|x]; r*x -> rx, z -> z1b
  maybeT(T_g1rz);
  {
    GP p{};
    p.A0 = y1; p.lda0 = 1024; p.A1 = xb16; p.lda1 = 1024; p.ksplit = 1024; p.K = 2048;
    p.B = G1rz; p.bg = g1_bg; p.xbuf = inputs;
    p.outb = rx; p.ldb = 1024; p.outb2 = z1b; p.ldb2 = 1024;
    gemm_bt<EP_SIGRX, 1><<<dim3(16, 32), blk, 0, stream>>>(p);
  }
  // 11. gate1 h + combine: o1 = (1-z)*x + z*tanh([y1|rx] @ [Wg;Ug])
  maybeT(T_g1g);
  {
    GP p{};
    p.A0 = y1; p.lda0 = 1024; p.A1 = rx; p.lda1 = 1024; p.ksplit = 1024; p.K = 2048;
    p.B = G1g; p.zbuf = z1b; p.xbuf = inputs;
    p.outf = o1; p.ldf = 1024; p.outb = o1b; p.ldb = 1024;
    gemm_bt<EP_GRU, 0><<<dim3(8, 64), blk, 0, stream>>>(p);
  }
  // 12. LN2(o1) -> x2
  ln_kernel<<<8192, blk, 0, stream>>>(o1, nullptr, ln2_g, ln2_b, x2, 1024,
                                      nullptr, 0, 1 << 30);
  // 13. mh = gelu(x2 @ W_m1 + b_m1)  (BIG)
  maybeT(T_m1);
  {
    GP p{};
    p.A0 = p.A1 = x2; p.lda0 = p.lda1 = 1024; p.ksplit = 1 << 30; p.K = 1024;
    p.B = Wm1T; p.bias = b_m1; p.outb = mh; p.ldb = 4096;
    gemm_bt<EP_GELU, 1><<<dim3(32, 32), blk, 0, stream>>>(p);
  }
  // 14. m2 = gelu(mh @ W_m2 + b_m2)
  maybeT(T_m2);
  {
    GP p{};
    p.A0 = p.A1 = mh; p.lda0 = p.lda1 = 4096; p.ksplit = 1 << 30; p.K = 4096;
    p.B = Wm2T; p.bias = b_m2; p.outb = m2; p.ldb = 1024;
    gemm_bt<EP_GELU, 0><<<dim3(8, 64), blk, 0, stream>>>(p);
  }
  // 15. gate2 r/z (BIG): [m2|o1b]; r*o1 -> rx, z -> z1b
  maybeT(T_g2rz);
  {
    GP p{};
    p.A0 = m2; p.lda0 = 1024; p.A1 = o1b; p.lda1 = 1024; p.ksplit = 1024; p.K = 2048;
    p.B = G2rz; p.bg = g2_bg; p.xbuf = o1;
    p.outb = rx; p.ldb = 1024; p.outb2 = z1b; p.ldb2 = 1024;
    gemm_bt<EP_SIGRX, 1><<<dim3(16, 32), blk, 0, stream>>>(p);
  }
  // 16. gate2 h + combine -> d_out (in-place over o1: own-element read/write)
  maybeT(T_g2g);
  {
    GP p{};
    p.A0 = m2; p.lda0 = 1024; p.A1 = rx; p.lda1 = 1024; p.ksplit = 1024; p.K = 2048;
    p.B = G2g; p.zbuf = z1b; p.xbuf = o1;
    p.outf = out; p.ldf = 1024; p.outb = nullptr;
    gemm_bt<EP_GRU, 0><<<dim3(8, 64), blk, 0, stream>>>(p);
  }
}

// Round 11
// 813.340 us; speedup vs baseline: 1.0871x; 1.0332x over previous
//
#include <hip/hip_runtime.h>
#include <cstdint>

// ---------------------------------------------------------------------------
// GatedTransformerXLLayer on MI355X (gfx950).
// D=1024, H=16, HD=64, FF=4096, CUR=256, MEM=256, BS=32, FULL=512.
// bf16 MFMA (16x16x32); GEMM: 3-slot ring LDS + counted vmcnt + raw
// s_barrier (T4) + XCD swizzle + setprio (T5) + T2 XOR swizzle; templated
// tile BIG=256x128 / 128x128. GELU epilogue = tanh-approx via __expf
// (erff cost ~35 VALU was half the m1/m2 kernel time; approx err <=1e-3).
// Fused attention with staged K/R/V, pre-scaled q, chunk skipping,
// single-pass __expf softmax with deferred 1/sum.
// ---------------------------------------------------------------------------

typedef __bf16 bf16;
typedef bf16 bf16x4 __attribute__((ext_vector_type(4)));
typedef bf16 bf16x8 __attribute__((ext_vector_type(8)));
typedef float f32x4 __attribute__((ext_vector_type(4)));

#define MFMA16(a, b, c) __builtin_amdgcn_mfma_f32_16x16x32_bf16((a), (b), (c), 0, 0, 0)

__device__ __forceinline__ void gl2lds16(const void* g, void* l) {
  __builtin_amdgcn_global_load_lds(
      (const __attribute__((address_space(1))) unsigned int*)g,
      (__attribute__((address_space(3))) unsigned int*)l, 16, 0, 0);
}

__device__ __forceinline__ bf16x8 ldg8(const bf16* p) { return *(const bf16x8*)p; }

// gelu(v) ~= v * sigmoid(1.59577*(v + 0.044715 v^3)); |err| <= ~1e-3,
// far under bf16 rounding. Clamped arg -> no inf/NaN.
__device__ __forceinline__ float fast_gelu(float v) {
  float u = v * (0.79788456f + 0.0356774081f * v * v);
  float uc = fminf(fmaxf(u, -15.f), 15.f);
  float e2 = __expf(2.0f * uc);
  return v * e2 / (e2 + 1.0f);
}

// XOR-swizzled index into a [16][512] bf16 wave-slice (u16 units).
__device__ __forceinline__ int sidx(int row, int col) {
  return (row * 512 + col) ^ ((row & 7) << 3);
}

// ---------------- LayerNorm (one row per block, 256 thr x float4) ----------
__global__ __launch_bounds__(256) void ln_kernel(
    const float* __restrict__ src0, const float* __restrict__ src1,
    const float* __restrict__ gam, const float* __restrict__ bet,
    bf16* __restrict__ out, long ldo,
    bf16* __restrict__ raw, long ldraw, int rawstart) {
  const int row = blockIdx.x;
  const int tid = threadIdx.x;
  const float* src = (src1 != nullptr && row >= rawstart)
                         ? (src1 + (long)(row - rawstart) * 1024)
                         : (src0 + (long)row * 1024);
  float4 v = ((const float4*)src)[tid];
  float s = v.x + v.y + v.z + v.w;
#pragma unroll
  for (int o = 32; o > 0; o >>= 1) s += __shfl_down(s, o);
  __shared__ float red[8];
  const int wv = tid >> 6, lane = tid & 63;
  if (lane == 0) red[wv] = s;
  __syncthreads();
  float mean = (red[0] + red[1] + red[2] + red[3]) * (1.0f / 1024.0f);
  float dx = v.x - mean, dy = v.y - mean, dz = v.z - mean, dw = v.w - mean;
  float ss = dx * dx + dy * dy + dz * dz + dw * dw;
#pragma unroll
  for (int o = 32; o > 0; o >>= 1) ss += __shfl_down(ss, o);
  if (lane == 0) red[4 + wv] = ss;
  __syncthreads();
  float var = (red[4] + red[5] + red[6] + red[7]) * (1.0f / 1024.0f);
  float rstd = rsqrtf(var + 1e-5f);
  int c = tid * 4;
  float4 g4 = ((const float4*)gam)[tid];
  float4 b4 = ((const float4*)bet)[tid];
  bf16x4 o4;
  o4[0] = (bf16)(dx * rstd * g4.x + b4.x);
  o4[1] = (bf16)(dy * rstd * g4.y + b4.y);
  o4[2] = (bf16)(dz * rstd * g4.z + b4.z);
  o4[3] = (bf16)(dw * rstd * g4.w + b4.w);
  *(bf16x4*)(out + (long)row * ldo + c) = o4;
  if (raw != nullptr && row >= rawstart) {
    bf16x4 r4;
    r4[0] = (bf16)v.x; r4[1] = (bf16)v.y; r4[2] = (bf16)v.z; r4[3] = (bf16)v.w;
    *(bf16x4*)(raw + (long)(row - rawstart) * ldraw + c) = r4;
  }
}

// ---------------- fp32 -> bf16 convert -------------------------------------
__global__ __launch_bounds__(256) void cvt_bf16_kernel(const float* __restrict__ s,
                                                       bf16* __restrict__ d) {
  long i = ((long)blockIdx.x * 256 + threadIdx.x) * 4;
  float4 v = *(const float4*)(s + i);
  bf16x4 o;
  o[0] = (bf16)v.x; o[1] = (bf16)v.y; o[2] = (bf16)v.z; o[3] = (bf16)v.w;
  *(bf16x4*)(d + i) = o;
}

// ---------------- batched weight transpose+convert -------------------------
struct TDesc { const float* src; bf16* dst; int N; int ldd; int start; };
struct TPack { TDesc d[18]; int nd; int total; };

__global__ __launch_bounds__(256) void wtrans_multi(TPack p) {
  __shared__ bf16 t[64][66];
  const int tile = blockIdx.x;
  int wi = 0;
#pragma unroll 1
  for (int i = 1; i < p.nd; ++i)
    if (tile >= p.d[i].start) wi = i;
  const float* src = p.d[wi].src;
  bf16* dst = p.d[wi].dst;
  const int N = p.d[wi].N;
  const long ldd = p.d[wi].ldd;
  const int local = tile - p.d[wi].start;
  const int tiles_x = N >> 6;
  const int n0 = (local % tiles_x) * 64, k0 = (local / tiles_x) * 64;
  const int tx = threadIdx.x & 63, ty = threadIdx.x >> 6;
#pragma unroll
  for (int i = 0; i < 64; i += 4)
    t[ty + i][tx] = (bf16)src[(long)(k0 + ty + i) * N + n0 + tx];
  __syncthreads();
#pragma unroll
  for (int i = 0; i < 64; i += 4)
    dst[(long)(n0 + ty + i) * ldd + k0 + tx] = t[tx][ty + i];
}

// ---------------- V transpose: Vbuf[t][1024] -> valT[(b*16+h)*64+d][j] -----
__global__ __launch_bounds__(256) void valt_kernel(const bf16* __restrict__ Vbuf,
                                                   bf16* __restrict__ valT) {
  __shared__ bf16 t[64][66];
  const int b = blockIdx.x, h = blockIdx.y, j0 = blockIdx.z * 64;
  const int jj = threadIdx.x >> 2, dg = (threadIdx.x & 3) * 16;
  const bf16* srcp = Vbuf + ((long)(j0 + jj) * 32 + b) * 1024 + h * 64 + dg;
  bf16x8 v0 = ldg8(srcp), v1 = ldg8(srcp + 8);
#pragma unroll
  for (int e = 0; e < 8; ++e) { t[jj][dg + e] = v0[e]; t[jj][dg + 8 + e] = v1[e]; }
  __syncthreads();
  const int dd = threadIdx.x >> 2, jg = (threadIdx.x & 3) * 16;
  bf16* dstp = valT + ((long)(b * 16 + h) * 64 + dd) * 512 + j0 + jg;
  bf16x8 o0, o1;
#pragma unroll
  for (int e = 0; e < 8; ++e) { o0[e] = t[jg + e][dd]; o1[e] = t[jg + 8 + e][dd]; }
  *(bf16x8*)dstp = o0;
  *(bf16x8*)(dstp + 8) = o1;
}

// ---------------- fused attention -----------------------------------------
__device__ __forceinline__ void stageKR(const char* rowbase, long strideB,
                                        bf16* stg, int tid) {
#pragma unroll
  for (int i = 0; i < 4; ++i) {
    const int slot = i * 256 + tid;
    const int row = slot >> 3;
    const int colb = ((slot << 4) & 127) ^ ((row & 7) << 4);
    gl2lds16(rowbase + (long)row * strideB + colb, (char*)stg + slot * 16);
  }
}
__device__ __forceinline__ void stageV(const char* rowbase, long strideB,
                                       bf16* stg, int tid) {
#pragma unroll
  for (int i = 0; i < 4; ++i) {
    const int slot = i * 256 + tid;
    const int row = slot >> 4;
    const int colb = ((slot << 4) & 255) ^ ((row & 7) << 4);
    gl2lds16(rowbase + (long)row * strideB + colb, (char*)stg + slot * 16);
  }
}
__device__ __forceinline__ bf16x8 rdKR(const bf16* stg, int rloc, int byteInRow) {
  const int addr = (rloc * 128 + byteInRow) ^ ((rloc & 7) << 4);
  return *(const bf16x8*)((const char*)stg + addr);
}
__device__ __forceinline__ bf16x8 rdV(const bf16* stg, int rloc, int byteInRow) {
  const int addr = (rloc * 256 + byteInRow) ^ ((rloc & 7) << 4);
  return *(const bf16x8*)((const char*)stg + addr);
}

__global__ __launch_bounds__(256, 2) void attn_kernel(
    const bf16* __restrict__ qb, const float* __restrict__ uvec,
    const float* __restrict__ vvec, const bf16* __restrict__ Kb,
    const bf16* __restrict__ rbf, const bf16* __restrict__ valT,
    bf16* __restrict__ a1out) {
  __shared__ __align__(16) bf16 s2[4][8192];   // 64KB wave-private S2/logit/P
  __shared__ __align__(16) bf16 stg[8192];     // 16KB shared staging
  const int tid = threadIdx.x;
  const int wv = tid >> 6, lane = tid & 63;
  const int l15 = lane & 15, lk = lane >> 4;
  const int bid = blockIdx.x;
  const int swzb = ((bid & 7) << 8) + (bid >> 3);  // nwg=2048, 256-chunks/XCD
  const int st = swzb & 3, h = (swzb >> 2) & 15, b = swzb >> 6;
  const int i0 = st * 64 + wv * 16;
  const long bh = (long)b * 16 + h;
  bf16* sw = s2[wv];
  const bool skipE = (st < 2);  // block-uniform masked-chunk skip

  const bf16* qp = qb + ((long)(i0 + l15) * 32 + b) * 1024 + h * 64 + lk * 8;
  bf16x8 q0 = ldg8(qp), q1 = ldg8(qp + 32);
  const float* up = uvec + h * 64 + lk * 8;
  const float* vp = vvec + h * 64 + lk * 8;
  bf16x8 a0u, a1u, a0v, a1v;
#pragma unroll
  for (int e = 0; e < 8; ++e) {
    float f0 = (float)q0[e], f1 = (float)q1[e];
    a0u[e] = (bf16)((f0 + up[e]) * 0.125f);
    a1u[e] = (bf16)((f1 + up[32 + e]) * 0.125f);
    a0v[e] = (bf16)((f0 + vp[e]) * 0.125f);
    a1v[e] = (bf16)((f1 + vp[32 + e]) * 0.125f);
  }

  // ---- Phase 1: S2 = (q+v)/8 R^T -> wave-private LDS, cols = raw index
#pragma unroll
  for (int c = 0; c < 4; ++c) {
    if (skipE && c == 0) continue;
    __syncthreads();
    stageKR((const char*)(rbf + (long)(c * 128) * 1024 + h * 64), 2048, stg, tid);
    __syncthreads();
#pragma unroll
    for (int jt = 0; jt < 8; ++jt) {
      bf16x8 b0 = rdKR(stg, jt * 16 + l15, lk * 16);
      bf16x8 b1 = rdKR(stg, jt * 16 + l15, 64 + lk * 16);
      f32x4 cc = {0.f, 0.f, 0.f, 0.f};
      cc = MFMA16(a0v, b0, cc);
      cc = MFMA16(a1v, b1, cc);
      const int jcol = (c * 8 + jt) * 16 + l15;
#pragma unroll
      for (int r = 0; r < 4; ++r) sw[sidx(lk * 4 + r, jcol)] = (bf16)cc[r];
    }
  }
  // ---- Phase 2: logits in-place (gather cols >= write col; wave-private)
#pragma unroll
  for (int c = 0; c < 4; ++c) {
    if (skipE && c == 3) continue;
    __syncthreads();
    stageKR((const char*)(Kb + ((long)(c * 128) * 32 + b) * 1024 + h * 64),
            65536, stg, tid);
    __syncthreads();
#pragma unroll
    for (int jt = 0; jt < 8; ++jt) {
      bf16x8 b0 = rdKR(stg, jt * 16 + l15, lk * 16);
      bf16x8 b1 = rdKR(stg, jt * 16 + l15, 64 + lk * 16);
      f32x4 cc = {0.f, 0.f, 0.f, 0.f};
      cc = MFMA16(a0u, b0, cc);
      cc = MFMA16(a1u, b1, cc);
      const int j = (c * 8 + jt) * 16 + l15;
      float lgv[4];
#pragma unroll
      for (int r = 0; r < 4; ++r) {
        const int i = i0 + lk * 4 + r;
        lgv[r] = (j <= i + 256)
                     ? (cc[r] + (float)sw[sidx(lk * 4 + r, j - i + 255)])
                     : -1e30f;
      }
#pragma unroll
      for (int r = 0; r < 4; ++r) sw[sidx(lk * 4 + r, j)] = (bf16)lgv[r];
    }
  }
  // ---- single-pass softmax, unnormalized; 1/sum deferred to PV epilogue
  float inv;
  {
    const int rr = lane & 15, pp = lane >> 4;
    const bool dead = skipE && (pp == 3);
    bf16x8 pk[16];
    float m = -3e38f;
    if (!dead) {
#pragma unroll
      for (int k = 0; k < 16; ++k)
        pk[k] = *(const bf16x8*)(sw + sidx(rr, pp * 128 + k * 8));
#pragma unroll
      for (int k = 0; k < 16; ++k)
#pragma unroll
        for (int e = 0; e < 8; ++e) m = fmaxf(m, (float)pk[k][e]);
    }
    m = fmaxf(m, __shfl_xor(m, 16));
    m = fmaxf(m, __shfl_xor(m, 32));
    float s = 0.f;
    if (!dead) {
#pragma unroll
      for (int k = 0; k < 16; ++k) {
        bf16x8 t;
#pragma unroll
        for (int e = 0; e < 8; ++e) {
          float ev = __expf((float)pk[k][e] - m);
          s += ev;
          t[e] = (bf16)ev;
        }
        *(bf16x8*)(sw + sidx(rr, pp * 128 + k * 8)) = t;
      }
    }
    s += __shfl_xor(s, 16);
    s += __shfl_xor(s, 32);
    inv = 1.0f / s;
  }
  // ---- Phase 3: O = (P V) * inv
  f32x4 oacc[4] = {};
  const char* vbase = (const char*)(valT + bh * 64 * 512);
#pragma unroll
  for (int c = 0; c < 4; ++c) {
    if (skipE && c == 3) continue;
    __syncthreads();
    stageV(vbase + c * 256, 1024, stg, tid);
    __syncthreads();
#pragma unroll
    for (int ksl = 0; ksl < 4; ++ksl) {
      const int ks = c * 4 + ksl;
      bf16x8 pa = *(const bf16x8*)(sw + sidx(l15, ks * 32 + lk * 8));
#pragma unroll
      for (int nt = 0; nt < 4; ++nt) {
        bf16x8 vb = rdV(stg, nt * 16 + l15, ksl * 64 + lk * 16);
        oacc[nt] = MFMA16(pa, vb, oacc[nt]);
      }
    }
  }
  float invr[4];
#pragma unroll
  for (int r = 0; r < 4; ++r) invr[r] = __shfl(inv, lk * 4 + r);
#pragma unroll
  for (int nt = 0; nt < 4; ++nt)
#pragma unroll
    for (int r = 0; r < 4; ++r) {
      const long t = (long)(i0 + lk * 4 + r) * 32 + b;
      a1out[t * 1024 + h * 64 + nt * 16 + l15] = (bf16)(oacc[nt][r] * invr[r]);
    }
}

// ---------------- templated ring GEMM with fused epilogues -----------------
// BIG=1: 256x128 tile, per-wave 128x64 (acc[8][4]); BIG=0: 128x128, 64x64.
// 3-slot ring, counted vmcnt(ALOADS+2), raw s_barrier, T2 swizzle, setprio.
enum { EP_B16 = 0, EP_KV2 = 1, EP_GELU = 2, EP_SIGRX = 3, EP_GRU = 4 };

struct GP {
  const bf16* A0; const bf16* A1;   // A split at k=ksplit (concat-K GEMMs)
  long lda0, lda1; int ksplit; int K;
  const bf16* B;                    // [N][K] bf16 (W^T), row stride K
  const float* bias;
  const float* bg;                  // EP_SIGRX
  const float* xbuf;                // EP_SIGRX (r*x), EP_GRU (combine x), f32
  const bf16* zbuf;                 // EP_GRU (z, bf16)
  float* outf; long ldf;
  bf16* outb; long ldb;
  bf16* outb2; long ldb2;
};

#define G_STAGE(BB, K0)                                                       \
  {                                                                           \
    const int k0_ = (K0);                                                     \
    _Pragma("unroll") for (int ii = 0; ii < ALOADS; ++ii) {                   \
      const int r_ = ii * 64 + (tid >> 2);                                    \
      const bf16* ag_ = (k0_ < p.ksplit)                                      \
          ? p.A0 + (m0 + r_) * p.lda0 + k0_ + skkx                            \
          : p.A1 + (m0 + r_) * p.lda1 + (k0_ - p.ksplit) + skkx;              \
      gl2lds16(ag_, As[BB] + (long)r_ * 32 + skk);                            \
    }                                                                         \
    gl2lds16(Bg0 + k0_, Bs[BB] + sdstB);                                      \
    gl2lds16(Bg1 + k0_, Bs[BB] + 64 * 32 + sdstB);                            \
  }

#define G_SUBITER(BB, TCUR)                                                   \
  if ((TCUR) < nt) {                                                          \
    bf16x8 af[MI], bfr[4];                                                    \
    _Pragma("unroll") for (int i = 0; i < MI; ++i)                            \
      af[i] = *(const bf16x8*)(As[BB] + (wr * (BM / 2) + i * 16 + l15) * 32 + lkx8); \
    _Pragma("unroll") for (int j = 0; j < 4; ++j)                             \
      bfr[j] = *(const bf16x8*)(Bs[BB] + (wc * 64 + j * 16 + l15) * 32 + lkx8); \
    if ((TCUR) + 2 < nt) G_STAGE((((BB) + 2) % 3), ((TCUR) + 2) * 32);        \
    __builtin_amdgcn_s_setprio(1);                                            \
    _Pragma("unroll") for (int i = 0; i < MI; ++i)                            \
      _Pragma("unroll") for (int j = 0; j < 4; ++j)                           \
          acc[i][j] = MFMA16(af[i], bfr[j], acc[i][j]);                       \
    __builtin_amdgcn_s_setprio(0);                                            \
    if ((TCUR) + 1 < nt) {                                                    \
      if ((TCUR) + 2 < nt)                                                    \
        asm volatile("s_waitcnt vmcnt(%0)" ::"i"(ALOADS + 2) : "memory");     \
      else                                                                    \
        asm volatile("s_waitcnt vmcnt(0)" ::: "memory");                      \
      __builtin_amdgcn_s_barrier();                                           \
    }                                                                         \
  }

template <int EP, int BIG>
__global__ __launch_bounds__(256, BIG ? 2 : 3) void gemm_bt(GP p) {
  constexpr int BM = BIG ? 256 : 128;
  constexpr int MI = BIG ? 8 : 4;
  constexpr int ALOADS = BIG ? 4 : 2;
  __shared__ __align__(16) bf16 As[3][BM * 32];
  __shared__ __align__(16) bf16 Bs[3][128 * 32];
  const int tid = threadIdx.x;
  const int lane = tid & 63;
  const int wv = tid >> 6;
  const int wr = wv >> 1, wc = wv & 1;
  const int l15 = lane & 15, lk = lane >> 4;
  const int lkx8 = (lk ^ ((l15 >> 1) & 3)) * 8;   // T2 swizzled read chunk
  const int nx = gridDim.x;
  const int nwg = nx * gridDim.y;
  const int bid = blockIdx.y * nx + blockIdx.x;
  const int qq = nwg >> 3, rr = nwg & 7, xc = bid & 7, loc = bid >> 3;
  const int swz = (xc < rr ? xc * (qq + 1) : rr * (qq + 1) + (xc - rr) * qq) + loc;
  const long n0 = (long)(swz % nx) * 128;
  const long m0 = (long)(swz / nx) * BM;
  const int skk = (tid & 3) * 8;                        // linear gl2lds dest
  const int skkx = ((tid & 3) ^ ((tid >> 3) & 3)) * 8;  // inverse-swz source
  const long sdstB = (long)(tid >> 2) * 32 + skk;

  const bf16* Bg0 = p.B + (n0 + (tid >> 2)) * (long)p.K + skkx;
  const bf16* Bg1 = p.B + (n0 + (tid >> 2) + 64) * (long)p.K + skkx;

  f32x4 acc[MI][4] = {};
  const int nt = p.K >> 5;

  // prologue: T0 -> slot0, T1 -> slot1; wait T0 landed
  G_STAGE(0, 0);
  G_STAGE(1, 32);
  asm volatile("s_waitcnt vmcnt(%0)" ::"i"(ALOADS + 2) : "memory");
  __builtin_amdgcn_s_barrier();

#pragma unroll 1
  for (int t = 0; t < nt; t += 3) {
    G_SUBITER(0, t);
    G_SUBITER(1, t + 1);
    G_SUBITER(2, t + 2);
  }

#pragma unroll
  for (int i = 0; i < MI; ++i) {
#pragma unroll
    for (int j = 0; j < 4; ++j) {
#pragma unroll
      for (int r = 0; r < 4; ++r) {
        const long row = m0 + wr * (BM / 2) + i * 16 + lk * 4 + r;
        const long col = n0 + wc * 64 + j * 16 + l15;
        float v = acc[i][j][r];
        if constexpr (EP == EP_B16) {
          v += p.bias[col];
          p.outb[row * p.ldb + col] = (bf16)v;
        } else if constexpr (EP == EP_KV2) {
          v += p.bias[col];
          if (col < 1024) p.outb[row * p.ldb + col] = (bf16)v;          // K
          else p.outb2[row * p.ldb2 + (col - 1024)] = (bf16)v;          // V
        } else if constexpr (EP == EP_GELU) {
          v += p.bias[col];
          p.outb[row * p.ldb + col] = (bf16)fast_gelu(v);
        } else if constexpr (EP == EP_SIGRX) {
          if (col >= 1024) {
            float sg = 1.0f / (1.0f + __expf(-(v - p.bg[col - 1024])));
            p.outb2[row * p.ldb2 + (col - 1024)] = (bf16)sg;            // z
          } else {
            float sg = 1.0f / (1.0f + __expf(-v));
            p.outb[row * p.ldb + col] = (bf16)(sg * p.xbuf[row * 1024 + col]);  // r*x
          }
        } else if constexpr (EP == EP_GRU) {
          float z = (float)p.zbuf[row * 1024 + col];
          float x = p.xbuf[row * 1024 + col];
          float vc = fminf(fmaxf(v, -15.f), 15.f);
          float e2 = __expf(2.0f * vc);
          float th = (e2 - 1.0f) / (e2 + 1.0f);
          float o = (1.0f - z) * x + z * th;
          p.outf[row * p.ldf + col] = o;
          if (p.outb != nullptr) p.outb[row * p.ldb + col] = (bf16)o;
        }
      }
    }
  }
}

// ---------------------------------------------------------------------------
extern "C" void kernel_launch(void* const* d_in, const int* in_sizes, int n_in,
                              void* d_out, int out_size, void* d_ws, size_t ws_size,
                              hipStream_t stream) {
  const float* inputs = (const float*)d_in[0];
  const float* posemb = (const float*)d_in[1];
  const float* u_in = (const float*)d_in[2];
  const float* v_in = (const float*)d_in[3];
  const float* memory = (const float*)d_in[4];
  // d_in[5] = mask: analytic (unmasked iff j <= i+256), not read.
  const float* ln1_g = (const float*)d_in[6];
  const float* ln1_b = (const float*)d_in[7];
  const float* ln2_g = (const float*)d_in[8];
  const float* ln2_b = (const float*)d_in[9];
  const float* W_kv = (const float*)d_in[10];
  const float* b_kv = (const float*)d_in[11];
  const float* W_q = (const float*)d_in[12];
  const float* b_q = (const float*)d_in[13];
  const float* W_pos = (const float*)d_in[14];
  const float* b_pos = (const float*)d_in[15];
  const float* W_o = (const float*)d_in[16];
  const float* b_o = (const float*)d_in[17];
  const float* g1_Wr = (const float*)d_in[18];
  const float* g1_Ur = (const float*)d_in[19];
  const float* g1_Wz = (const float*)d_in[20];
  const float* g1_Uz = (const float*)d_in[21];
  const float* g1_Wg = (const float*)d_in[22];
  const float* g1_Ug = (const float*)d_in[23];
  const float* g1_bg = (const float*)d_in[24];
  const float* g2_Wr = (const float*)d_in[25];
  const float* g2_Ur = (const float*)d_in[26];
  const float* g2_Wz = (const float*)d_in[27];
  const float* g2_Uz = (const float*)d_in[28];
  const float* g2_Wg = (const float*)d_in[29];
  const float* g2_Ug = (const float*)d_in[30];
  const float* g2_bg = (const float*)d_in[31];
  const float* W_m1 = (const float*)d_in[32];
  const float* b_m1 = (const float*)d_in[33];
  const float* W_m2 = (const float*)d_in[34];
  const float* b_m2 = (const float*)d_in[35];
  float* out = (float*)d_out;
  float* o1 = out;  // f32 o1 parked in d_out (fully rewritten s11, read 12/15/16)

  const size_t MB = 1024UL * 1024UL;
  const size_t sizeB = 154 * MB;
  const size_t sizeA = 196 * MB;
  const bool A = (ws_size >= sizeA);
  if (!A && ws_size < sizeB) {  // canary: absmax ~3.4e38 => ws too small
    hipMemsetAsync(d_out, 0x7F, 256, stream);
    return;
  }

  char* w = (char*)d_ws;
  size_t off = 0;
  auto take = [&](size_t bytes) { char* p = w + off; off += bytes; return p; };
  char* RW = take(A ? 50 * MB : 8 * MB);
  bf16* posbf = (bf16*)take(1 * MB);
  bf16* rbf = (bf16*)take(1 * MB);
  char* R3 = take(32 * MB);   // x1(1-4) | valT(7-8) | y1@0(9-11), x2@16M(12-13) | m2@0(14-16)
  char* R45 = take(64 * MB);  // Kbuf@0 + Vbuf@32M (4-8) | mh 64MB (13-14)
  char* R6 = take(16 * MB);   // xb16(1-10) | o1b(11-16)
  char* R7 = take(16 * MB);   // qb(5-8) | rx(10-16)
  char* R8 = take(16 * MB);   // a1b(8-9) | z1b(10-16)

  bf16* WT = (bf16*)RW;
  bf16* WkvT  = A ? (bf16*)(RW + 0 * MB)  : WT;
  bf16* WqT   = A ? (bf16*)(RW + 4 * MB)  : WT;
  bf16* WposT = A ? (bf16*)(RW + 6 * MB)  : WT;
  bf16* WoT   = A ? (bf16*)(RW + 8 * MB)  : WT;
  bf16* G1rz  = A ? (bf16*)(RW + 10 * MB) : WT;
  bf16* G1g   = A ? (bf16*)(RW + 18 * MB) : WT;
  bf16* Wm1T  = A ? (bf16*)(RW + 22 * MB) : WT;
  bf16* Wm2T  = A ? (bf16*)(RW + 30 * MB) : WT;
  bf16* G2rz  = A ? (bf16*)(RW + 38 * MB) : WT;
  bf16* G2g   = A ? (bf16*)(RW + 46 * MB) : WT;

  bf16* x1 = (bf16*)R3;
  bf16* valT = (bf16*)R3;
  bf16* y1 = (bf16*)R3;
  bf16* x2 = (bf16*)(R3 + 16 * MB);
  bf16* m2 = (bf16*)R3;
  bf16* Kbuf = (bf16*)R45;
  bf16* Vbuf = (bf16*)(R45 + 32 * MB);
  bf16* mh = (bf16*)R45;
  bf16* xb16 = (bf16*)R6;
  bf16* o1b = (bf16*)R6;
  bf16* qb = (bf16*)R7;
  bf16* rx = (bf16*)R7;
  bf16* a1b = (bf16*)R8;
  bf16* z1b = (bf16*)R8;

  dim3 blk(256);
  auto addT = [](TPack& p, const float* src, bf16* dst, int K, int N, int ldd) {
    TDesc& d = p.d[p.nd++];
    d.src = src; d.dst = dst; d.N = N; d.ldd = ldd; d.start = p.total;
    p.total += (N / 64) * (K / 64);
  };
  auto runT = [&](TPack& p) {
    wtrans_multi<<<dim3(p.total), blk, 0, stream>>>(p);
  };
  auto T_kv = [&](TPack& p) { addT(p, W_kv, WkvT, 1024, 2048, 1024); };
  auto T_q = [&](TPack& p) { addT(p, W_q, WqT, 1024, 1024, 1024); };
  auto T_pos = [&](TPack& p) { addT(p, W_pos, WposT, 1024, 1024, 1024); };
  auto T_o = [&](TPack& p) { addT(p, W_o, WoT, 1024, 1024, 1024); };
  auto T_g1rz = [&](TPack& p) {
    addT(p, g1_Wr, G1rz, 1024, 1024, 2048);
    addT(p, g1_Ur, G1rz + 1024, 1024, 1024, 2048);
    addT(p, g1_Wz, G1rz + 1024L * 2048, 1024, 1024, 2048);
    addT(p, g1_Uz, G1rz + 1024L * 2048 + 1024, 1024, 1024, 2048);
  };
  auto T_g1g = [&](TPack& p) {
    addT(p, g1_Wg, G1g, 1024, 1024, 2048);
    addT(p, g1_Ug, G1g + 1024, 1024, 1024, 2048);
  };
  auto T_m1 = [&](TPack& p) { addT(p, W_m1, Wm1T, 1024, 4096, 1024); };
  auto T_m2 = [&](TPack& p) { addT(p, W_m2, Wm2T, 4096, 1024, 4096); };
  auto T_g2rz = [&](TPack& p) {
    addT(p, g2_Wr, G2rz, 1024, 1024, 2048);
    addT(p, g2_Ur, G2rz + 1024, 1024, 1024, 2048);
    addT(p, g2_Wz, G2rz + 1024L * 2048, 1024, 1024, 2048);
    addT(p, g2_Uz, G2rz + 1024L * 2048 + 1024, 1024, 1024, 2048);
  };
  auto T_g2g = [&](TPack& p) {
    addT(p, g2_Wg, G2g, 1024, 1024, 2048);
    addT(p, g2_Ug, G2g + 1024, 1024, 1024, 2048);
  };
  auto maybeT = [&](auto builder) {
    if (!A) { TPack p{}; builder(p); runT(p); }
  };

  if (A) {  // one batched transpose for all 18 weights
    TPack p{};
    T_kv(p); T_q(p); T_pos(p); T_o(p); T_g1rz(p); T_g1g(p);
    T_m1(p); T_m2(p); T_g2rz(p); T_g2g(p);
    runT(p);
  }

  // 1. LN1 over [memory; inputs] -> x1; raw inputs bf16 -> xb16
  ln_kernel<<<16384, blk, 0, stream>>>(memory, inputs, ln1_g, ln1_b, x1, 1024,
                                       xb16, 1024, 8192);
  // 2. pos_embedding -> bf16
  cvt_bf16_kernel<<<512, blk, 0, stream>>>(posemb, posbf);

  // 4. kv GEMM (BIG): K -> Kbuf, V -> Vbuf
  maybeT(T_kv);
  {
    GP p{};
    p.A0 = p.A1 = x1; p.lda0 = p.lda1 = 1024; p.ksplit = 1 << 30; p.K = 1024;
    p.B = WkvT; p.bias = b_kv; p.outb = Kbuf; p.ldb = 1024;
    p.outb2 = Vbuf; p.ldb2 = 1024;
    gemm_bt<EP_KV2, 1><<<dim3(16, 64), blk, 0, stream>>>(p);
  }
  // 5. q = inputs @ W_q + b_q -> qb
  maybeT(T_q);
  {
    GP p{};
    p.A0 = p.A1 = xb16; p.lda0 = p.lda1 = 1024; p.ksplit = 1 << 30; p.K = 1024;
    p.B = WqT; p.bias = b_q; p.outb = qb; p.ldb = 1024;
    gemm_bt<EP_B16, 0><<<dim3(8, 64), blk, 0, stream>>>(p);
  }
  // 6. r = pos_embedding @ W_pos + b_pos -> rbf
  maybeT(T_pos);
  {
    GP p{};
    p.A0 = p.A1 = posbf; p.lda0 = p.lda1 = 1024; p.ksplit = 1 << 30; p.K = 1024;
    p.B = WposT; p.bias = b_pos; p.outb = rbf; p.ldb = 1024;
    gemm_bt<EP_B16, 0><<<dim3(8, 4), blk, 0, stream>>>(p);
  }
  // 7. V transpose (x1 dead; valT overlays R3)
  valt_kernel<<<dim3(32, 16, 8), blk, 0, stream>>>(Vbuf, valT);
  // 8. fused attention -> a1b
  attn_kernel<<<dim3(2048), blk, 0, stream>>>(qb, u_in, v_in, Kbuf, rbf, valT, a1b);
  // 9. y1 = gelu(a1 @ W_o + b_o)
  maybeT(T_o);
  {
    GP p{};
    p.A0 = p.A1 = a1b; p.lda0 = p.lda1 = 1024; p.ksplit = 1 << 30; p.K = 1024;
    p.B = WoT; p.bias = b_o; p.outb = y1; p.ldb = 1024;
    gemm_bt<EP_GELU, 0><<<dim3(8, 64), blk, 0, stream>>>(p);
  }
  // 10. gate1 r/z (BIG): [y1|x]; r*x -> rx, z -> z1b
  maybeT(T_g1rz);
  {
    GP p{};
    p.A0 = y1; p.lda0 = 1024; p.A1 = xb16; p.lda1 = 1024; p.ksplit = 1024; p.K = 2048;
    p.B = G1rz; p.bg = g1_bg; p.xbuf = inputs;
    p.outb = rx; p.ldb = 1024; p.outb2 = z1b; p.ldb2 = 1024;
    gemm_bt<EP_SIGRX, 1><<<dim3(16, 32), blk, 0, stream>>>(p);
  }
  // 11. gate1 h + combine: o1 = (1-z)*x + z*tanh([y1|rx] @ [Wg;Ug])
  maybeT(T_g1g);
  {
    GP p{};
    p.A0 = y1; p.lda0 = 1024; p.A1 = rx; p.lda1 = 1024; p.ksplit = 1024; p.K = 2048;
    p.B = G1g; p.zbuf = z1b; p.xbuf = inputs;
    p.outf = o1; p.ldf = 1024; p.outb = o1b; p.ldb = 1024;
    gemm_bt<EP_GRU, 0><<<dim3(8, 64), blk, 0, stream>>>(p);
  }
  // 12. LN2(o1) -> x2
  ln_kernel<<<8192, blk, 0, stream>>>(o1, nullptr, ln2_g, ln2_b, x2, 1024,
                                      nullptr, 0, 1 << 30);
  // 13. mh = gelu(x2 @ W_m1 + b_m1)  (BIG)
  maybeT(T_m1);
  {
    GP p{};
    p.A0 = p.A1 = x2; p.lda0 = p.lda1 = 1024; p.ksplit = 1 << 30; p.K = 1024;
    p.B = Wm1T; p.bias = b_m1; p.outb = mh; p.ldb = 4096;
    gemm_bt<EP_GELU, 1><<<dim3(32, 32), blk, 0, stream>>>(p);
  }
  // 14. m2 = gelu(mh @ W_m2 + b_m2)
  maybeT(T_m2);
  {
    GP p{};
    p.A0 = p.A1 = mh; p.lda0 = p.lda1 = 4096; p.ksplit = 1 << 30; p.K = 4096;
    p.B = Wm2T; p.bias = b_m2; p.outb = m2; p.ldb = 1024;
    gemm_bt<EP_GELU, 0><<<dim3(8, 64), blk, 0, stream>>>(p);
  }
  // 15. gate2 r/z (BIG): [m2|o1b]; r*o1 -> rx, z -> z1b
  maybeT(T_g2rz);
  {
    GP p{};
    p.A0 = m2; p.lda0 = 1024; p.A1 = o1b; p.lda1 = 1024; p.ksplit = 1024; p.K = 2048;
    p.B = G2rz; p.bg = g2_bg; p.xbuf = o1;
    p.outb = rx; p.ldb = 1024; p.outb2 = z1b; p.ldb2 = 1024;
    gemm_bt<EP_SIGRX, 1><<<dim3(16, 32), blk, 0, stream>>>(p);
  }
  // 16. gate2 h + combine -> d_out (in-place over o1: own-element read/write)
  maybeT(T_g2g);
  {
    GP p{};
    p.A0 = m2; p.lda0 = 1024; p.A1 = rx; p.lda1 = 1024; p.ksplit = 1024; p.K = 2048;
    p.B = G2g; p.zbuf = z1b; p.xbuf = o1;
    p.outf = out; p.ldf = 1024; p.outb = nullptr;
    gemm_bt<EP_GRU, 0><<<dim3(8, 64), blk, 0, stream>>>(p);
  }
}